// Round 17
// baseline (241.983 us; speedup 1.0000x reference)
//
#include <hip/hip_runtime.h>

// Problem constants (fixed by the reference)
#define NN     100000      // nodes
#define EE     1600000     // edges
#define NB     8           // graphs
#define BLK    12500       // nodes per graph
#define HID    128
#define KC     4
#define CHUNKS 196         // ceil(12500/64)
#define NTILE  49          // dst-ranges of 256 nodes per graph
#define NBIN   392         // 8 graphs x 49 tiles
#define GCAPS  5120        // per-bin capacity (mean 4081, sigma ~64)

typedef __attribute__((ext_vector_type(8))) short bf16x8;
typedef __attribute__((ext_vector_type(4))) float f32x4;

__device__ __forceinline__ ushort f2bf(float f) {
  uint u = __float_as_uint(f);
  return (ushort)((u + 0x7FFFu + ((u >> 16) & 1u)) >> 16);  // RNE
}
__device__ __forceinline__ float bf2f(ushort h) {
  return __uint_as_float(((uint)h) << 16);
}

#define GLL16(g, l) \
  __builtin_amdgcn_global_load_lds((const __attribute__((address_space(1))) void*)(g), \
                                   (__attribute__((address_space(3))) void*)(l), 16, 0, 0)

// ---------------------------------------------------------------- K0a: x -> bf16
__global__ __launch_bounds__(256) void k_prep_x(const float4* __restrict__ x4,
                                                ushort* __restrict__ xb) {
  int i = blockIdx.x * 256 + threadIdx.x;  // 3.2M float4s exactly
  float4 v = x4[i];
  ushort4 r;
  r.x = f2bf(v.x); r.y = f2bf(v.y); r.z = f2bf(v.z); r.w = f2bf(v.w);
  *(ushort4*)(xb + (size_t)i * 4) = r;
}

// ---------------------------------------------------------------- K0b: Wt[col][k], k<128 = Wrel1, k>=128 = Wroot1
__global__ __launch_bounds__(256) void k_prep_w(const float* __restrict__ Wrel1,
                                                const float* __restrict__ Wroot1,
                                                ushort* __restrict__ Wt) {
  int col = blockIdx.x, k = threadIdx.x;
  float v = (k < 128) ? Wrel1[k * 128 + col] : Wroot1[(k - 128) * 128 + col];
  Wt[col * 256 + k] = f2bf(v);
}

// ---------------------------------------------------------------- K1a: edges -> 392 (graph, dst-range) sub-buckets
__global__ __launch_bounds__(256) void k_bucket2(const int* __restrict__ ei,
                                                 int* __restrict__ sbcnt,
                                                 uint* __restrict__ gbuf) {
  __shared__ uint stage[8192];
  __shared__ int cnt[NBIN], start[NBIN + 1], rbase[NBIN];
  __shared__ int gtot[8], gb[8];
  const int t = threadIdx.x;
  for (int b = t; b < NBIN; b += 256) cnt[b] = 0;
  __syncthreads();
  const int e0 = blockIdx.x * 8192;
  uint pk[32]; int br[32];
#pragma unroll
  for (int i = 0; i < 32; ++i) {
    int e = e0 + i * 256 + t;
    bool val = (e < EE);
    int src = 0, dst = 0;
    if (val) {
      src = __builtin_nontemporal_load(ei + e);
      dst = __builtin_nontemporal_load(ei + EE + e);
    }
    int g = dst / BLK;
    int dl = dst - g * BLK;
    int sl = src - g * BLK;
    int bin = g * NTILE + (dl >> 8);
    pk[i] = ((uint)sl << 16) | (uint)dl;
    br[i] = val ? ((bin << 14) | atomicAdd(&cnt[bin], 1)) : -1;
  }
  __syncthreads();
  if (t < 8) {
    int s = 0;
    for (int k = 0; k < NTILE; ++k) s += cnt[t * NTILE + k];
    gtot[t] = s;
  }
  __syncthreads();
  if (t == 0) {
    int s = 0;
    for (int g = 0; g < 8; ++g) { gb[g] = s; s += gtot[g]; }
    start[NBIN] = s;
  }
  __syncthreads();
  if (t < 8) {
    int run = gb[t];
    for (int k = 0; k < NTILE; ++k) { start[t * NTILE + k] = run; run += cnt[t * NTILE + k]; }
  }
  __syncthreads();
  for (int b = t; b < NBIN; b += 256) rbase[b] = atomicAdd(&sbcnt[b], cnt[b]);
#pragma unroll
  for (int i = 0; i < 32; ++i) {
    if (br[i] >= 0) {
      int bin = br[i] >> 14, rank = br[i] & 16383;
      stage[start[bin] + rank] = pk[i];
    }
  }
  __syncthreads();
  // per-bin segmented flush
  for (int b = t; b < NBIN; b += 256) {
    const int n = cnt[b];
    const int s0 = start[b];
    uint* dst = gbuf + (size_t)b * GCAPS + rbase[b];
    for (int i = 0; i < n; ++i) dst[i] = stage[s0 + i];
  }
}

// ---------------------------------------------------------------- K1b: exclusive scan of bin sizes
__global__ __launch_bounds__(512) void k_scan392(const int* __restrict__ sbcnt,
                                                 int* __restrict__ sbbase) {
  __shared__ int sd[512];
  const int t = threadIdx.x;
  int v = (t < NBIN) ? sbcnt[t] : 0;
  sd[t] = v;
  __syncthreads();
  for (int s = 1; s < 512; s <<= 1) {
    int x = (t >= s) ? sd[t - s] : 0;
    __syncthreads();
    sd[t] += x;
    __syncthreads();
  }
  if (t < NBIN) sbbase[t] = sd[t] - v;
}

// ---------------------------------------------------------------- K1c: per-bin LDS counting sort -> dense CSR segment + rowptr + count
__global__ __launch_bounds__(256) void k_csr_tile(const uint* __restrict__ gbuf,
                                                  const int* __restrict__ sbcnt,
                                                  const int* __restrict__ sbbase,
                                                  int* __restrict__ rowptr,
                                                  int* __restrict__ count,
                                                  int* __restrict__ csr) {
  const int g = blockIdx.x & 7;     // XCD-local per graph
  const int tile = blockIdx.x >> 3; // 0..48
  const int bin = g * NTILE + tile;
  const int m = sbcnt[bin];
  const int base = sbbase[bin];
  const int n0t = tile * 256;
  const int nt = min(256, BLK - n0t);
  __shared__ uint ent[GCAPS];
  __shared__ ushort srt[GCAPS];
  __shared__ int cnt[256], scn[256], cur[256];
  const int t = threadIdx.x;
  cnt[t] = 0;
  __syncthreads();
  const uint* buf = gbuf + (size_t)bin * GCAPS;
  for (int i = t; i < m; i += 256) {
    uint pk = buf[i];
    ent[i] = pk;
    atomicAdd(&cnt[(int)(pk & 0xFFFFu) - n0t], 1);
  }
  __syncthreads();
  int v = cnt[t];
  scn[t] = v;
  __syncthreads();
  for (int s = 1; s < 256; s <<= 1) {
    int x = (t >= s) ? scn[t - s] : 0;
    __syncthreads();
    scn[t] += x;
    __syncthreads();
  }
  int excl = scn[t] - v;
  cur[t] = excl;
  if (t < nt) {
    rowptr[g * BLK + n0t + t] = base + excl;
    count[g * BLK + n0t + t] = v;
  }
  __syncthreads();
  for (int i = t; i < m; i += 256) {
    uint pk = ent[i];
    int p = atomicAdd(&cur[(int)(pk & 0xFFFFu) - n0t], 1);
    srt[p] = (ushort)(pk >> 16);
  }
  __syncthreads();
  const int nb = g * BLK;
  for (int i = t; i < m; i += 256)
    csr[base + i] = nb + (int)srt[i];  // dense coalesced
}

// ---------------------------------------------------------------- K2: agg[n] = sum_{e: dst=n} x[src]
// R17: ONE WAVE PER NODE. The CSR index list is wave-uniform -> index reads
// become s_load (scalar pipe, 0 VALU); row base = SALU; loads are
// global_load_dword saddr-form with a fixed lane voffset (0 VALU addr math,
// no shfl). Each lane owns one dword (2 bf16): hi bf16 is already an f32
// after AND 0xFFFF0000; lo needs SHL 16 -> 2 VALU/value (was ~6.5). Masked
// 8-wide batches (uniform tail-select to zrow) keep 8 loads in flight.
__global__ __launch_bounds__(256) void k_agg3(const ushort* __restrict__ xb,
                                              const int* __restrict__ count,
                                              const int* __restrict__ rowptr,
                                              const int* __restrict__ csr,
                                              const ushort* __restrict__ zrow,
                                              ushort* __restrict__ aggb) {
  const int g = blockIdx.x & 7;     // graph = XCD (round-robin)
  const int j = blockIdx.x >> 3;    // 0..3124
  const int wid = threadIdx.x >> 6; // wave 0..3
  const int lane = threadIdx.x & 63;
  const int ln = j * 4 + wid;       // 0..12499 exactly (BLK % 4 == 0)
  const int node = g * BLK + ln;
  const int deg = count[node];
  const int* sl = csr + rowptr[node];

  float alo = 0.f, ahi = 0.f;
  const int nb8 = (deg + 7) >> 3;
  for (int b = 0; b < nb8; ++b) {
    const ushort* rp[8];
#pragma unroll
    for (int q = 0; q < 8; ++q) {
      const int ee = b * 8 + q;                 // wave-uniform
      const int ee2 = (ee < deg) ? ee : deg - 1; // deg>=1 inside loop
      const int si = sl[ee2];                    // uniform -> s_load
      rp[q] = (ee < deg) ? (xb + (size_t)si * HID) : zrow;  // SALU select
    }
    uint v[8];
#pragma unroll
    for (int q = 0; q < 8; ++q)
      v[q] = *(const uint*)(rp[q] + lane * 2);   // saddr + lane voffset
#pragma unroll
    for (int q = 0; q < 8; ++q) {
      ahi += __uint_as_float(v[q] & 0xFFFF0000u);
      alo += __uint_as_float(v[q] << 16);
    }
  }
  ushort2 r;
  r.x = f2bf(alo);  // value index 2*lane
  r.y = f2bf(ahi);  // value index 2*lane+1
  *(ushort2*)(aggb + (size_t)node * HID + lane * 2) = r;
}

// ---------------------------------------------------------------- K3a: GEMM half — stage A (DMA) + MFMA + bias/relu -> hbuf (dense bf16)
__global__ __launch_bounds__(256) void k_gemm(
    const ushort* __restrict__ aggb, const ushort* __restrict__ xb,
    const ushort* __restrict__ Wt, const float* __restrict__ brel1,
    ushort* __restrict__ hbuf) {
  __shared__ ushort Aag_s[64][128];  // 16 KB, linear (DMA dest)
  __shared__ ushort Ax_s[64][128];   // 16 KB, linear (DMA dest)
  __shared__ ushort hLb[64][136];    // h tile bf16 (pad 136)

  const int t = threadIdx.x;
  const int bi = blockIdx.x;
  const int bG = bi & 7;
  const int chunk = bi >> 3;
  const int node0 = bG * BLK + chunk * 64;
  int nrows = BLK - chunk * 64;
  if (nrows > 64) nrows = 64;

  const int w = t >> 6;
  const int l = t & 63;

  // async stage: 8 global_load_lds per wave (4 agg + 4 x tiles)
  {
    const int sub = l >> 4;
    const int c16 = l & 15;
#pragma unroll
    for (int i = 0; i < 4; ++i) {
      const int j = w * 4 + i;
      const int row = j * 4 + sub;
      const int rs = (row < nrows) ? row : (nrows - 1);
      const int boff = (c16 * 16) ^ ((row & 7) << 4);
      const ushort* ga = aggb + (size_t)(node0 + rs) * HID + (boff >> 1);
      const ushort* gx = xb + (size_t)(node0 + rs) * HID + (boff >> 1);
      GLL16(ga, &Aag_s[j * 4][0]);
      GLL16(gx, &Ax_s[j * 4][0]);
    }
  }

  const int m16 = l & 15;
  const int gq = l >> 4;

  bf16x8 Breg[8][2];
#pragma unroll
  for (int kt = 0; kt < 8; ++kt)
#pragma unroll
    for (int fc = 0; fc < 2; ++fc)
      Breg[kt][fc] =
          *(const bf16x8*)(Wt + (size_t)(32 * w + 16 * fc + m16) * 256 + kt * 32 + 8 * gq);

  f32x4 acc[4][2];
#pragma unroll
  for (int fr = 0; fr < 4; ++fr)
#pragma unroll
    for (int fc = 0; fc < 2; ++fc) acc[fr][fc] = (f32x4){0.f, 0.f, 0.f, 0.f};

  asm volatile("s_waitcnt vmcnt(0)" ::: "memory");
  __syncthreads();

#pragma unroll
  for (int kt = 0; kt < 8; ++kt) {
    const int k4 = kt & 3;
    bf16x8 af[4];
#pragma unroll
    for (int fr = 0; fr < 4; ++fr) {
      const int r = 16 * fr + m16;
      const int ci = (k4 * 32 + gq * 8) ^ ((r & 7) << 3);
      af[fr] = (kt < 4) ? *(const bf16x8*)&Aag_s[r][ci]
                        : *(const bf16x8*)&Ax_s[r][ci];
    }
#pragma unroll
    for (int fr = 0; fr < 4; ++fr)
#pragma unroll
      for (int fc = 0; fc < 2; ++fc)
        acc[fr][fc] = __builtin_amdgcn_mfma_f32_16x16x32_bf16(af[fr], Breg[kt][fc],
                                                              acc[fr][fc], 0, 0, 0);
  }

  const float bc0 = brel1[32 * w + m16];
  const float bc1 = brel1[32 * w + 16 + m16];
#pragma unroll
  for (int fr = 0; fr < 4; ++fr)
#pragma unroll
    for (int fc = 0; fc < 2; ++fc)
#pragma unroll
      for (int r = 0; r < 4; ++r)
        hLb[16 * fr + 4 * gq + r][32 * w + 16 * fc + m16] =
            f2bf(fmaxf(acc[fr][fc][r] + (fc ? bc1 : bc0), 0.f));
  __syncthreads();

  // dense h store: thread t -> row t>>2, 64 B chunk (t&3)
  {
    const int row = t >> 2;
    const int ch = (t & 3) * 32;
    if (row < nrows) {
      ushort* dst = hbuf + (size_t)(node0 + row) * HID + ch;
      const ushort* src = &hLb[row][ch];
#pragma unroll
      for (int q = 0; q < 4; ++q)
        *(bf16x8*)(dst + q * 8) = *(const bf16x8*)(src + q * 8);
    }
  }
}

// ---------------------------------------------------------------- K3b: epilogue half — read h, softmax + pooled reductions
__global__ __launch_bounds__(256) void k_epi(
    const ushort* __restrict__ hbuf, const float* __restrict__ Wpool,
    const float* __restrict__ bpool, const int* __restrict__ count,
    float* __restrict__ s_out, float* __restrict__ out_pool,
    float* __restrict__ ss_g, float* __restrict__ den_g) {
  __shared__ ushort hLb[64][136];
  __shared__ float outL[KC][HID];
  __shared__ float ssL[16];
  __shared__ float denL;

  const int t = threadIdx.x;
  const int bi = blockIdx.x;
  const int bG = bi & 7;
  const int chunk = bi >> 3;
  const int node0 = bG * BLK + chunk * 64;
  int nrows = BLK - chunk * 64;
  if (nrows > 64) nrows = 64;

  // dense h load: thread t -> row t>>2, 64 B chunk (t&3)
  {
    const int row = t >> 2;
    const int ch = (t & 3) * 32;
    const int rs = (row < nrows) ? row : (nrows - 1);
    const ushort* src = hbuf + (size_t)(node0 + rs) * HID + ch;
    ushort* dst = &hLb[row][ch];
#pragma unroll
    for (int q = 0; q < 4; ++q)
      *(bf16x8*)(dst + q * 8) = *(const bf16x8*)(src + q * 8);
  }

  for (int i = t; i < KC * HID; i += 256) ((float*)outL)[i] = 0.f;
  if (t < 16) ssL[t] = 0.f;
  if (t == 0) denL = 0.f;
  __syncthreads();

  const int g4 = t >> 4;
  const int c0 = (t & 15) << 2;
  const int li = t & 15;

  float h[4][8];
#pragma unroll
  for (int r = 0; r < 4; ++r) {
    ushort4 v0 = *(const ushort4*)&hLb[g4 * 4 + r][c0];
    ushort4 v1 = *(const ushort4*)&hLb[g4 * 4 + r][c0 + 64];
    h[r][0] = bf2f(v0.x); h[r][1] = bf2f(v0.y); h[r][2] = bf2f(v0.z); h[r][3] = bf2f(v0.w);
    h[r][4] = bf2f(v1.x); h[r][5] = bf2f(v1.y); h[r][6] = bf2f(v1.z); h[r][7] = bf2f(v1.w);
  }

  // pooling head: p = h @ Wpool
  float wp[8][4];
#pragma unroll
  for (int j = 0; j < 8; ++j) {
    int col = c0 + (j & 3) + (j >> 2) * 64;
    float4 v = *(const float4*)(Wpool + col * 4);
    wp[j][0] = v.x; wp[j][1] = v.y; wp[j][2] = v.z; wp[j][3] = v.w;
  }
  float pp[4][4];
#pragma unroll
  for (int r = 0; r < 4; ++r)
#pragma unroll
    for (int k = 0; k < 4; ++k) pp[r][k] = 0.f;
#pragma unroll
  for (int r = 0; r < 4; ++r)
#pragma unroll
    for (int j = 0; j < 8; ++j)
#pragma unroll
      for (int k = 0; k < 4; ++k) pp[r][k] = fmaf(h[r][j], wp[j][k], pp[r][k]);
#pragma unroll
  for (int m = 1; m <= 8; m <<= 1)
#pragma unroll
    for (int r = 0; r < 4; ++r)
#pragma unroll
      for (int k = 0; k < 4; ++k) pp[r][k] += __shfl_xor(pp[r][k], m);

  float4 bp4 = *(const float4*)bpool;
  float bp[4] = {bp4.x, bp4.y, bp4.z, bp4.w};
  float sv[4][4];
#pragma unroll
  for (int r = 0; r < 4; ++r) {
    float p[4];
#pragma unroll
    for (int k = 0; k < 4; ++k) p[k] = pp[r][k] + bp[k];
    float mx = fmaxf(fmaxf(p[0], p[1]), fmaxf(p[2], p[3]));
    float e0 = expf(p[0] - mx), e1 = expf(p[1] - mx), e2 = expf(p[2] - mx), e3 = expf(p[3] - mx);
    float inv = 1.f / (e0 + e1 + e2 + e3);
    float valid = (g4 * 4 + r < nrows) ? 1.f : 0.f;
    sv[r][0] = e0 * inv * valid; sv[r][1] = e1 * inv * valid;
    sv[r][2] = e2 * inv * valid; sv[r][3] = e3 * inv * valid;
  }

  // write s
  {
    int rW = li >> 2, kW = li & 3;
    if (g4 * 4 + rW < nrows) {
      int node = node0 + g4 * 4 + rW;
      float val = 0.f;
#pragma unroll
      for (int rr = 0; rr < 4; ++rr)
#pragma unroll
        for (int kk = 0; kk < 4; ++kk)
          if (li == rr * 4 + kk) val = sv[rr][kk];
      s_out[node * 4 + kW] = val;
    }
  }

  // ss[b][k1][k2]
  {
    int k1 = li >> 2, k2 = li & 3;
    float a1[4], a2[4];
#pragma unroll
    for (int rr = 0; rr < 4; ++rr) {
      float v1 = 0.f, v2 = 0.f;
#pragma unroll
      for (int kk = 0; kk < 4; ++kk) {
        if (k1 == kk) v1 = sv[rr][kk];
        if (k2 == kk) v2 = sv[rr][kk];
      }
      a1[rr] = v1; a2[rr] = v2;
    }
    float ssv = a1[0] * a2[0] + a1[1] * a2[1] + a1[2] * a2[2] + a1[3] * a2[3];
    atomicAdd(&ssL[li], ssv);
  }

  // den += deg * ||s||^2
  if (li == 0) {
    float dent = 0.f;
#pragma unroll
    for (int rr = 0; rr < 4; ++rr) {
      int rowg = g4 * 4 + rr;
      if (rowg < nrows) {
        float dg = (float)count[node0 + rowg];
        dent += dg * (sv[rr][0] * sv[rr][0] + sv[rr][1] * sv[rr][1] +
                      sv[rr][2] * sv[rr][2] + sv[rr][3] * sv[rr][3]);
      }
    }
    atomicAdd(&denL, dent);
  }

  // out[k][c] += s[r][k]*h[r][c]
  float po[4][8];
#pragma unroll
  for (int k = 0; k < 4; ++k)
#pragma unroll
    for (int c = 0; c < 8; ++c) po[k][c] = 0.f;
#pragma unroll
  for (int k = 0; k < 4; ++k)
#pragma unroll
    for (int rr = 0; rr < 4; ++rr)
#pragma unroll
      for (int c = 0; c < 8; ++c) po[k][c] = fmaf(sv[rr][k], h[rr][c], po[k][c]);
#pragma unroll
  for (int k = 0; k < 4; ++k)
#pragma unroll
    for (int c = 0; c < 8; ++c) {
      po[k][c] += __shfl_xor(po[k][c], 16);
      po[k][c] += __shfl_xor(po[k][c], 32);
    }
  if ((t & 63) < 16) {
#pragma unroll
    for (int k = 0; k < 4; ++k)
#pragma unroll
      for (int c = 0; c < 8; ++c)
        atomicAdd(&outL[k][c0 + (c & 3) + (c >> 2) * 64], po[k][c]);
  }

  __syncthreads();
  for (int i = t; i < KC * HID; i += 256)
    atomicAdd(&out_pool[bG * KC * HID + i], ((const float*)outL)[i]);
  if (t < 16) atomicAdd(&ss_g[bG * 16 + t], ssL[t]);
  if (t == 0) atomicAdd(&den_g[bG], denL);
}

// ---------------------------------------------------------------- K4: out_adj — masked 8-wide batches (no serial remainder)
__global__ __launch_bounds__(256) void k_adj2(const int* __restrict__ count,
                                              const int* __restrict__ rowptr,
                                              const int* __restrict__ csr,
                                              const float* __restrict__ s,
                                              const float* __restrict__ zf,
                                              float* __restrict__ adjraw) {
  __shared__ float accL[4][2][16];  // [wave][graph-within-block][k1*4+k2]
  const int t = threadIdx.x;
  if (t < 128) ((float*)accL)[t] = 0.f;
  __syncthreads();
  const int node = blockIdx.x * 256 + t;
  const int g0 = (blockIdx.x * 256) / BLK;
  if (node < NN) {
    const int gi = node / BLK - g0;  // 0 or 1
    const int deg = count[node];
    const int* sl = csr + rowptr[node];
    float a[8][4];
#pragma unroll
    for (int q = 0; q < 8; ++q)
#pragma unroll
      for (int c = 0; c < 4; ++c) a[q][c] = 0.f;
    const int nb8 = (deg + 7) >> 3;
    for (int b = 0; b < nb8; ++b) {
      const float* p[8];
#pragma unroll
      for (int q = 0; q < 8; ++q) {
        int ee = b * 8 + q;
        int si = (ee < deg) ? sl[ee] : 0;
        p[q] = (ee < deg) ? (s + (size_t)si * 4) : zf;
      }
      float4 v[8];
#pragma unroll
      for (int q = 0; q < 8; ++q) v[q] = *(const float4*)p[q];
#pragma unroll
      for (int q = 0; q < 8; ++q) {
        a[q][0] += v[q].x; a[q][1] += v[q].y; a[q][2] += v[q].z; a[q][3] += v[q].w;
      }
    }
    float t0 = 0.f, t1 = 0.f, t2 = 0.f, t3 = 0.f;
#pragma unroll
    for (int q = 0; q < 8; ++q) { t0 += a[q][0]; t1 += a[q][1]; t2 += a[q][2]; t3 += a[q][3]; }
    float4 sn = *(const float4*)(s + (size_t)node * 4);
    float* base = accL[t >> 6][gi];
#pragma unroll
    for (int i = 0; i < 16; ++i) {
      int idx = (i + t) & 15;  // stagger: 4-way instead of 64-way contention
      int hi = idx >> 2, lo = idx & 3;
      float a1 = (hi == 0) ? sn.x : (hi == 1) ? sn.y : (hi == 2) ? sn.z : sn.w;
      float b1 = (lo == 0) ? t0 : (lo == 1) ? t1 : (lo == 2) ? t2 : t3;
      atomicAdd(base + idx, a1 * b1);
    }
  }
  __syncthreads();
  if (t < 32) {
    int gi = t >> 4, i = t & 15, gg = g0 + gi;
    if (gg < NB) {
      float v = accL[0][gi][i] + accL[1][gi][i] + accL[2][gi][i] + accL[3][gi][i];
      atomicAdd(&adjraw[gg * 16 + i], v);
    }
  }
}

// ---------------------------------------------------------------- K5a: per-graph tail
__global__ __launch_bounds__(128) void k_graph(
    const float* __restrict__ out_pool, const float* __restrict__ adjraw,
    const float* __restrict__ den_g, const float* __restrict__ ss_g,
    const float* __restrict__ Wrel3, const float* __restrict__ brel3,
    const float* __restrict__ Wroot3, const float* __restrict__ Wlin1,
    const float* __restrict__ blin1, const float* __restrict__ Wlin2,
    const float* __restrict__ blin2, float* __restrict__ d_out,
    float* __restrict__ scratch) {
  const int b = blockIdx.x, t = threadIdx.x;
  __shared__ float adjL[16], adjnL[16], dL[4];
  __shared__ float osL[128], msL[128], x2mL[128], x3L[128];
  if (t < 16) adjL[t] = adjraw[b * 16 + t];
  __syncthreads();
  if (t < 4) {
    float srow = 0.f;
#pragma unroll
    for (int l = 0; l < 4; ++l)
      if (l != t) srow += adjL[t * 4 + l];
    dL[t] = sqrtf(srow) + 1e-15f;
  }
  __syncthreads();
  if (t < 16) {
    int k1 = t >> 2, k2 = t & 3;
    float az = (k1 == k2) ? 0.f : adjL[t];
    float an = az / (dL[k2] * dL[k1]);
    adjnL[t] = an;
    d_out[400018 + b * 16 + t] = an;
  }
  __syncthreads();
  float o0 = out_pool[b * 512 + 0 * 128 + t];
  float o1 = out_pool[b * 512 + 1 * 128 + t];
  float o2 = out_pool[b * 512 + 2 * 128 + t];
  float o3 = out_pool[b * 512 + 3 * 128 + t];
  float m0 = adjnL[0] * o0 + adjnL[1] * o1 + adjnL[2] * o2 + adjnL[3] * o3;
  float m1 = adjnL[4] * o0 + adjnL[5] * o1 + adjnL[6] * o2 + adjnL[7] * o3;
  float m2 = adjnL[8] * o0 + adjnL[9] * o1 + adjnL[10] * o2 + adjnL[11] * o3;
  float m3 = adjnL[12] * o0 + adjnL[13] * o1 + adjnL[14] * o2 + adjnL[15] * o3;
  osL[t] = o0 + o1 + o2 + o3;
  msL[t] = m0 + m1 + m2 + m3;
  __syncthreads();
  float accc = brel3[t];
  for (int j = 0; j < 128; ++j)
    accc += 0.25f * (msL[j] * Wrel3[j * 128 + t] + osL[j] * Wroot3[j * 128 + t]);
  x2mL[t] = accc;
  __syncthreads();
  float a2 = blin1[t];
  for (int j = 0; j < 128; ++j) a2 += x2mL[j] * Wlin1[j * 128 + t];
  x3L[t] = fmaxf(a2, 0.f);
  __syncthreads();
  if (t < 2) {
    float lg = blin2[t];
    for (int j = 0; j < 128; ++j) lg += x3L[j] * Wlin2[j * 2 + t];
    scratch[b * 2 + t] = lg;
  }
  if (t == 0) {
    float tr = adjL[0] + adjL[5] + adjL[10] + adjL[15];
    scratch[16 + b] = tr / den_g[b];
    float n2 = 0.f;
    for (int i = 0; i < 16; ++i) { float v = ss_g[b * 16 + i]; n2 += v * v; }
    float nn = sqrtf(n2);
    float od = 0.f;
    for (int i = 0; i < 16; ++i) {
      float v = ss_g[b * 16 + i] / nn - (((i >> 2) == (i & 3)) ? 0.5f : 0.f);
      od += v * v;
    }
    scratch[24 + b] = sqrtf(od);
  }
}

// ---------------------------------------------------------------- K5b: losses + log_softmax
__global__ void k_final(const float* __restrict__ scratch, float* __restrict__ d_out) {
  if (threadIdx.x == 0 && blockIdx.x == 0) {
    float mc = 0.f, oo = 0.f;
    for (int b = 0; b < NB; ++b) { mc += scratch[16 + b]; oo += scratch[24 + b]; }
    d_out[16] = -(mc / (float)NB);
    d_out[17] = oo / (float)NB;
    for (int b = 0; b < NB; ++b) {
      float l0 = scratch[2 * b], l1 = scratch[2 * b + 1];
      float m = fmaxf(l0, l1);
      float lse = m + logf(expf(l0 - m) + expf(l1 - m));
      d_out[2 * b] = l0 - lse;
      d_out[2 * b + 1] = l1 - lse;
    }
  }
}

// ---------------------------------------------------------------- launch
extern "C" void kernel_launch(void* const* d_in, const int* in_sizes, int n_in,
                              void* d_out, int out_size, void* d_ws, size_t ws_size,
                              hipStream_t stream) {
  (void)in_sizes; (void)n_in; (void)out_size; (void)ws_size;
  const float* x      = (const float*)d_in[0];
  const int*   ei     = (const int*)d_in[1];
  const float* Wroot1 = (const float*)d_in[3];
  const float* Wrel1  = (const float*)d_in[4];
  const float* brel1  = (const float*)d_in[5];
  const float* Wpool  = (const float*)d_in[6];
  const float* bpool  = (const float*)d_in[7];
  const float* Wrel3  = (const float*)d_in[8];
  const float* brel3  = (const float*)d_in[9];
  const float* Wroot3 = (const float*)d_in[10];
  const float* Wlin1  = (const float*)d_in[11];
  const float* blin1  = (const float*)d_in[12];
  const float* Wlin2  = (const float*)d_in[13];
  const float* blin2  = (const float*)d_in[14];
  float* out = (float*)d_out;

  char* ws = (char*)d_ws;
  float*  out_pool = (float*)(ws + 0);          //  16384 B (memset)
  float*  ss_g     = (float*)(ws + 16384);      //    512 B (memset)
  float*  adjraw   = (float*)(ws + 16896);      //    512 B (memset)
  float*  den_g    = (float*)(ws + 17408);      //     32 B (memset)
  float*  scratch  = (float*)(ws + 17440);      //    128 B (memset)
  int*    sbcnt    = (int*)(ws + 17568);        //   1568 B (memset)
  ushort* zrow     = (ushort*)(ws + 19136);     //    256 B zeros (memset)
  float*  zf       = (float*)(ws + 19392);      //     16 B zeros (memset)
  int*    sbbase   = (int*)(ws + 19648);        //   1600 B
  int*    count    = (int*)(ws + 21248);        // 400000 B
  int*    rowptr   = (int*)(ws + 421248);       // 400016 B
  ushort* Wt       = (ushort*)(ws + 821264);    //  65536 B [128][256]
  int*    csr      = (int*)(ws + 886800);       // 6400000 B [E]
  ushort* xb       = (ushort*)(ws + 7286800);   // 25600000 B [N][128] bf16
  ushort* aggb     = (ushort*)(ws + 32886800);  // 25600000 B [N][128] bf16
  uint*   gbuf     = (uint*)(ws + 58486800);    // 8028160 B
  ushort* hbuf     = (ushort*)(ws + 66514960);  // 25600000 B [N][128] bf16

  hipMemsetAsync(ws, 0, 19648, stream);
  k_prep_x<<<12500, 256, 0, stream>>>((const float4*)x, xb);
  k_prep_w<<<128, 256, 0, stream>>>(Wrel1, Wroot1, Wt);
  k_bucket2<<<196, 256, 0, stream>>>(ei, sbcnt, gbuf);
  k_scan392<<<1, 512, 0, stream>>>(sbcnt, sbbase);
  k_csr_tile<<<NBIN, 256, 0, stream>>>(gbuf, sbcnt, sbbase, rowptr, count, csr);
  k_agg3<<<8 * (BLK / 4), 256, 0, stream>>>(xb, count, rowptr, csr, zrow, aggb);
  k_gemm<<<NB * CHUNKS, 256, 0, stream>>>(aggb, xb, Wt, brel1, hbuf);
  k_epi<<<NB * CHUNKS, 256, 0, stream>>>(hbuf, Wpool, bpool, count, out + 18,
                                         out_pool, ss_g, den_g);
  k_adj2<<<(NN + 255) / 256, 256, 0, stream>>>(count, rowptr, csr, out + 18, zf, adjraw);
  k_graph<<<NB, 128, 0, stream>>>(out_pool, adjraw, den_g, ss_g, Wrel3, brel3, Wroot3,
                                  Wlin1, blin1, Wlin2, blin2, out, scratch);
  k_final<<<1, 64, 0, stream>>>(scratch, out);
}

// Round 18
// 206.579 us; speedup vs baseline: 1.1714x; 1.1714x over previous
//
#include <hip/hip_runtime.h>

// Problem constants (fixed by the reference)
#define NN     100000      // nodes
#define EE     1600000     // edges
#define NB     8           // graphs
#define BLK    12500       // nodes per graph
#define HID    128
#define KC     4
#define CHUNKS 196         // ceil(12500/64)
#define NTILE  49          // dst-ranges of 256 nodes per graph
#define NBIN   392         // 8 graphs x 49 tiles
#define GCAPS  5120        // per-bin capacity (mean 4081, sigma ~64)

typedef __attribute__((ext_vector_type(8))) short bf16x8;
typedef __attribute__((ext_vector_type(4))) float f32x4;

__device__ __forceinline__ ushort f2bf(float f) {
  uint u = __float_as_uint(f);
  return (ushort)((u + 0x7FFFu + ((u >> 16) & 1u)) >> 16);  // RNE
}
__device__ __forceinline__ float bf2f(ushort h) {
  return __uint_as_float(((uint)h) << 16);
}

#define GLL16(g, l) \
  __builtin_amdgcn_global_load_lds((const __attribute__((address_space(1))) void*)(g), \
                                   (__attribute__((address_space(3))) void*)(l), 16, 0, 0)

// ---------------------------------------------------------------- K0a: x -> bf16
__global__ __launch_bounds__(256) void k_prep_x(const float4* __restrict__ x4,
                                                ushort* __restrict__ xb) {
  int i = blockIdx.x * 256 + threadIdx.x;  // 3.2M float4s exactly
  float4 v = x4[i];
  ushort4 r;
  r.x = f2bf(v.x); r.y = f2bf(v.y); r.z = f2bf(v.z); r.w = f2bf(v.w);
  *(ushort4*)(xb + (size_t)i * 4) = r;
}

// ---------------------------------------------------------------- K0b: Wt[col][k], k<128 = Wrel1, k>=128 = Wroot1
__global__ __launch_bounds__(256) void k_prep_w(const float* __restrict__ Wrel1,
                                                const float* __restrict__ Wroot1,
                                                ushort* __restrict__ Wt) {
  int col = blockIdx.x, k = threadIdx.x;
  float v = (k < 128) ? Wrel1[k * 128 + col] : Wroot1[(k - 128) * 128 + col];
  Wt[col * 256 + k] = f2bf(v);
}

// ---------------------------------------------------------------- K1a: edges -> 392 (graph, dst-range) sub-buckets
__global__ __launch_bounds__(256) void k_bucket2(const int* __restrict__ ei,
                                                 int* __restrict__ sbcnt,
                                                 uint* __restrict__ gbuf) {
  __shared__ uint stage[8192];
  __shared__ int cnt[NBIN], start[NBIN + 1], rbase[NBIN];
  __shared__ int gtot[8], gb[8];
  const int t = threadIdx.x;
  for (int b = t; b < NBIN; b += 256) cnt[b] = 0;
  __syncthreads();
  const int e0 = blockIdx.x * 8192;
  uint pk[32]; int br[32];
#pragma unroll
  for (int i = 0; i < 32; ++i) {
    int e = e0 + i * 256 + t;
    bool val = (e < EE);
    int src = 0, dst = 0;
    if (val) {
      src = __builtin_nontemporal_load(ei + e);
      dst = __builtin_nontemporal_load(ei + EE + e);
    }
    int g = dst / BLK;
    int dl = dst - g * BLK;
    int sl = src - g * BLK;
    int bin = g * NTILE + (dl >> 8);
    pk[i] = ((uint)sl << 16) | (uint)dl;
    br[i] = val ? ((bin << 14) | atomicAdd(&cnt[bin], 1)) : -1;
  }
  __syncthreads();
  if (t < 8) {
    int s = 0;
    for (int k = 0; k < NTILE; ++k) s += cnt[t * NTILE + k];
    gtot[t] = s;
  }
  __syncthreads();
  if (t == 0) {
    int s = 0;
    for (int g = 0; g < 8; ++g) { gb[g] = s; s += gtot[g]; }
    start[NBIN] = s;
  }
  __syncthreads();
  if (t < 8) {
    int run = gb[t];
    for (int k = 0; k < NTILE; ++k) { start[t * NTILE + k] = run; run += cnt[t * NTILE + k]; }
  }
  __syncthreads();
  for (int b = t; b < NBIN; b += 256) rbase[b] = atomicAdd(&sbcnt[b], cnt[b]);
#pragma unroll
  for (int i = 0; i < 32; ++i) {
    if (br[i] >= 0) {
      int bin = br[i] >> 14, rank = br[i] & 16383;
      stage[start[bin] + rank] = pk[i];
    }
  }
  __syncthreads();
  // per-bin segmented flush
  for (int b = t; b < NBIN; b += 256) {
    const int n = cnt[b];
    const int s0 = start[b];
    uint* dst = gbuf + (size_t)b * GCAPS + rbase[b];
    for (int i = 0; i < n; ++i) dst[i] = stage[s0 + i];
  }
}

// ---------------------------------------------------------------- K1b: exclusive scan of bin sizes
__global__ __launch_bounds__(512) void k_scan392(const int* __restrict__ sbcnt,
                                                 int* __restrict__ sbbase) {
  __shared__ int sd[512];
  const int t = threadIdx.x;
  int v = (t < NBIN) ? sbcnt[t] : 0;
  sd[t] = v;
  __syncthreads();
  for (int s = 1; s < 512; s <<= 1) {
    int x = (t >= s) ? sd[t - s] : 0;
    __syncthreads();
    sd[t] += x;
    __syncthreads();
  }
  if (t < NBIN) sbbase[t] = sd[t] - v;
}

// ---------------------------------------------------------------- K1c: per-bin LDS counting sort -> dense CSR segment + rowptr + count
__global__ __launch_bounds__(256) void k_csr_tile(const uint* __restrict__ gbuf,
                                                  const int* __restrict__ sbcnt,
                                                  const int* __restrict__ sbbase,
                                                  int* __restrict__ rowptr,
                                                  int* __restrict__ count,
                                                  int* __restrict__ csr) {
  const int g = blockIdx.x & 7;     // XCD-local per graph
  const int tile = blockIdx.x >> 3; // 0..48
  const int bin = g * NTILE + tile;
  const int m = sbcnt[bin];
  const int base = sbbase[bin];
  const int n0t = tile * 256;
  const int nt = min(256, BLK - n0t);
  __shared__ uint ent[GCAPS];
  __shared__ ushort srt[GCAPS];
  __shared__ int cnt[256], scn[256], cur[256];
  const int t = threadIdx.x;
  cnt[t] = 0;
  __syncthreads();
  const uint* buf = gbuf + (size_t)bin * GCAPS;
  for (int i = t; i < m; i += 256) {
    uint pk = buf[i];
    ent[i] = pk;
    atomicAdd(&cnt[(int)(pk & 0xFFFFu) - n0t], 1);
  }
  __syncthreads();
  int v = cnt[t];
  scn[t] = v;
  __syncthreads();
  for (int s = 1; s < 256; s <<= 1) {
    int x = (t >= s) ? scn[t - s] : 0;
    __syncthreads();
    scn[t] += x;
    __syncthreads();
  }
  int excl = scn[t] - v;
  cur[t] = excl;
  if (t < nt) {
    rowptr[g * BLK + n0t + t] = base + excl;
    count[g * BLK + n0t + t] = v;
  }
  __syncthreads();
  for (int i = t; i < m; i += 256) {
    uint pk = ent[i];
    int p = atomicAdd(&cur[(int)(pk & 0xFFFFu) - n0t], 1);
    srt[p] = (ushort)(pk >> 16);
  }
  __syncthreads();
  const int nb = g * BLK;
  for (int i = t; i < m; i += 256)
    csr[base + i] = nb + (int)srt[i];  // dense coalesced
}

// ---------------------------------------------------------------- K2: agg[n] = sum_{e: dst=n} x[src]
// R18: R16 half-wave structure (8 nodes/block, best measured) + dword
// bit-trick accumulation: the HI bf16 of a dword is a valid f32 after
// AND 0xFFFF0000; the LO after SHL 16 -> 4 VALU/dword (was 6 with ushort4
// extraction + bf2f). Masked 8-wide batches keep 8 loads in flight.
__global__ __launch_bounds__(256) void k_agg2(const ushort* __restrict__ xb,
                                              const int* __restrict__ count,
                                              const int* __restrict__ rowptr,
                                              const int* __restrict__ csr,
                                              const ushort* __restrict__ zrow,
                                              ushort* __restrict__ aggb) {
  const int xg = blockIdx.x & 7;
  const int j = blockIdx.x >> 3;
  const int half = threadIdx.x >> 5;  // 8 half-waves = 8 nodes per block
  const int lane = threadIdx.x & 31;
  const int ln = j * 8 + half;
  if (ln >= BLK) return;
  const int node = xg * BLK + ln;
  const int deg = count[node];
  const int* sl = csr + rowptr[node];
  int idx0 = (lane < deg) ? sl[lane] : 0;
  int idx1 = (32 + lane < deg) ? sl[32 + lane] : 0;
  const ushort* zr = zrow + lane * 4;

  // acc[q] = (lo0, hi0, lo1, hi1) for dwords 0,1 of this lane's 8 B chunk
  float4 acc[8];
#pragma unroll
  for (int q = 0; q < 8; ++q) acc[q] = (float4){0.f, 0.f, 0.f, 0.f};

  const int nb8 = (deg + 7) >> 3;
  for (int b = 0; b < nb8; ++b) {
    const int e = b * 8;
    const ushort* ps[8];
#pragma unroll
    for (int q = 0; q < 8; ++q) {
      int ee = e + q;
      int si = (ee < 32) ? __shfl(idx0, ee, 32)
             : ((ee < 64) ? __shfl(idx1, ee - 32, 32)
                          : ((ee < deg) ? sl[ee] : 0));
      ps[q] = (ee < deg) ? (xb + (size_t)si * HID + lane * 4) : zr;
    }
    uint2 v[8];
#pragma unroll
    for (int q = 0; q < 8; ++q) v[q] = *(const uint2*)ps[q];
#pragma unroll
    for (int q = 0; q < 8; ++q) {
      acc[q].x += __uint_as_float(v[q].x << 16);
      acc[q].y += __uint_as_float(v[q].x & 0xFFFF0000u);
      acc[q].z += __uint_as_float(v[q].y << 16);
      acc[q].w += __uint_as_float(v[q].y & 0xFFFF0000u);
    }
  }

  float lo0 = 0.f, hi0 = 0.f, lo1 = 0.f, hi1 = 0.f;
#pragma unroll
  for (int q = 0; q < 8; ++q) { lo0 += acc[q].x; hi0 += acc[q].y; lo1 += acc[q].z; hi1 += acc[q].w; }
  ushort4 r;
  r.x = f2bf(lo0); r.y = f2bf(hi0); r.z = f2bf(lo1); r.w = f2bf(hi1);
  *(ushort4*)(aggb + (size_t)node * HID + lane * 4) = r;
}

// ---------------------------------------------------------------- K3a: GEMM half — stage A (DMA) + MFMA + bias/relu -> hbuf (dense bf16)
__global__ __launch_bounds__(256) void k_gemm(
    const ushort* __restrict__ aggb, const ushort* __restrict__ xb,
    const ushort* __restrict__ Wt, const float* __restrict__ brel1,
    ushort* __restrict__ hbuf) {
  __shared__ ushort Aag_s[64][128];  // 16 KB, linear (DMA dest)
  __shared__ ushort Ax_s[64][128];   // 16 KB, linear (DMA dest)
  __shared__ ushort hLb[64][136];    // h tile bf16 (pad 136)

  const int t = threadIdx.x;
  const int bi = blockIdx.x;
  const int bG = bi & 7;
  const int chunk = bi >> 3;
  const int node0 = bG * BLK + chunk * 64;
  int nrows = BLK - chunk * 64;
  if (nrows > 64) nrows = 64;

  const int w = t >> 6;
  const int l = t & 63;

  // async stage: 8 global_load_lds per wave (4 agg + 4 x tiles)
  {
    const int sub = l >> 4;
    const int c16 = l & 15;
#pragma unroll
    for (int i = 0; i < 4; ++i) {
      const int j = w * 4 + i;
      const int row = j * 4 + sub;
      const int rs = (row < nrows) ? row : (nrows - 1);
      const int boff = (c16 * 16) ^ ((row & 7) << 4);
      const ushort* ga = aggb + (size_t)(node0 + rs) * HID + (boff >> 1);
      const ushort* gx = xb + (size_t)(node0 + rs) * HID + (boff >> 1);
      GLL16(ga, &Aag_s[j * 4][0]);
      GLL16(gx, &Ax_s[j * 4][0]);
    }
  }

  const int m16 = l & 15;
  const int gq = l >> 4;

  bf16x8 Breg[8][2];
#pragma unroll
  for (int kt = 0; kt < 8; ++kt)
#pragma unroll
    for (int fc = 0; fc < 2; ++fc)
      Breg[kt][fc] =
          *(const bf16x8*)(Wt + (size_t)(32 * w + 16 * fc + m16) * 256 + kt * 32 + 8 * gq);

  f32x4 acc[4][2];
#pragma unroll
  for (int fr = 0; fr < 4; ++fr)
#pragma unroll
    for (int fc = 0; fc < 2; ++fc) acc[fr][fc] = (f32x4){0.f, 0.f, 0.f, 0.f};

  asm volatile("s_waitcnt vmcnt(0)" ::: "memory");
  __syncthreads();

#pragma unroll
  for (int kt = 0; kt < 8; ++kt) {
    const int k4 = kt & 3;
    bf16x8 af[4];
#pragma unroll
    for (int fr = 0; fr < 4; ++fr) {
      const int r = 16 * fr + m16;
      const int ci = (k4 * 32 + gq * 8) ^ ((r & 7) << 3);
      af[fr] = (kt < 4) ? *(const bf16x8*)&Aag_s[r][ci]
                        : *(const bf16x8*)&Ax_s[r][ci];
    }
#pragma unroll
    for (int fr = 0; fr < 4; ++fr)
#pragma unroll
      for (int fc = 0; fc < 2; ++fc)
        acc[fr][fc] = __builtin_amdgcn_mfma_f32_16x16x32_bf16(af[fr], Breg[kt][fc],
                                                              acc[fr][fc], 0, 0, 0);
  }

  const float bc0 = brel1[32 * w + m16];
  const float bc1 = brel1[32 * w + 16 + m16];
#pragma unroll
  for (int fr = 0; fr < 4; ++fr)
#pragma unroll
    for (int fc = 0; fc < 2; ++fc)
#pragma unroll
      for (int r = 0; r < 4; ++r)
        hLb[16 * fr + 4 * gq + r][32 * w + 16 * fc + m16] =
            f2bf(fmaxf(acc[fr][fc][r] + (fc ? bc1 : bc0), 0.f));
  __syncthreads();

  // dense h store: thread t -> row t>>2, 64 B chunk (t&3)
  {
    const int row = t >> 2;
    const int ch = (t & 3) * 32;
    if (row < nrows) {
      ushort* dst = hbuf + (size_t)(node0 + row) * HID + ch;
      const ushort* src = &hLb[row][ch];
#pragma unroll
      for (int q = 0; q < 4; ++q)
        *(bf16x8*)(dst + q * 8) = *(const bf16x8*)(src + q * 8);
    }
  }
}

// ---------------------------------------------------------------- K3b: epilogue half — read h, softmax + pooled reductions
__global__ __launch_bounds__(256) void k_epi(
    const ushort* __restrict__ hbuf, const float* __restrict__ Wpool,
    const float* __restrict__ bpool, const int* __restrict__ count,
    float* __restrict__ s_out, float* __restrict__ out_pool,
    float* __restrict__ ss_g, float* __restrict__ den_g) {
  __shared__ ushort hLb[64][136];
  __shared__ float outL[KC][HID];
  __shared__ float ssL[16];
  __shared__ float denL;

  const int t = threadIdx.x;
  const int bi = blockIdx.x;
  const int bG = bi & 7;
  const int chunk = bi >> 3;
  const int node0 = bG * BLK + chunk * 64;
  int nrows = BLK - chunk * 64;
  if (nrows > 64) nrows = 64;

  // dense h load: thread t -> row t>>2, 64 B chunk (t&3)
  {
    const int row = t >> 2;
    const int ch = (t & 3) * 32;
    const int rs = (row < nrows) ? row : (nrows - 1);
    const ushort* src = hbuf + (size_t)(node0 + rs) * HID + ch;
    ushort* dst = &hLb[row][ch];
#pragma unroll
    for (int q = 0; q < 4; ++q)
      *(bf16x8*)(dst + q * 8) = *(const bf16x8*)(src + q * 8);
  }

  for (int i = t; i < KC * HID; i += 256) ((float*)outL)[i] = 0.f;
  if (t < 16) ssL[t] = 0.f;
  if (t == 0) denL = 0.f;
  __syncthreads();

  const int g4 = t >> 4;
  const int c0 = (t & 15) << 2;
  const int li = t & 15;

  float h[4][8];
#pragma unroll
  for (int r = 0; r < 4; ++r) {
    ushort4 v0 = *(const ushort4*)&hLb[g4 * 4 + r][c0];
    ushort4 v1 = *(const ushort4*)&hLb[g4 * 4 + r][c0 + 64];
    h[r][0] = bf2f(v0.x); h[r][1] = bf2f(v0.y); h[r][2] = bf2f(v0.z); h[r][3] = bf2f(v0.w);
    h[r][4] = bf2f(v1.x); h[r][5] = bf2f(v1.y); h[r][6] = bf2f(v1.z); h[r][7] = bf2f(v1.w);
  }

  // pooling head: p = h @ Wpool
  float wp[8][4];
#pragma unroll
  for (int j = 0; j < 8; ++j) {
    int col = c0 + (j & 3) + (j >> 2) * 64;
    float4 v = *(const float4*)(Wpool + col * 4);
    wp[j][0] = v.x; wp[j][1] = v.y; wp[j][2] = v.z; wp[j][3] = v.w;
  }
  float pp[4][4];
#pragma unroll
  for (int r = 0; r < 4; ++r)
#pragma unroll
    for (int k = 0; k < 4; ++k) pp[r][k] = 0.f;
#pragma unroll
  for (int r = 0; r < 4; ++r)
#pragma unroll
    for (int j = 0; j < 8; ++j)
#pragma unroll
      for (int k = 0; k < 4; ++k) pp[r][k] = fmaf(h[r][j], wp[j][k], pp[r][k]);
#pragma unroll
  for (int m = 1; m <= 8; m <<= 1)
#pragma unroll
    for (int r = 0; r < 4; ++r)
#pragma unroll
      for (int k = 0; k < 4; ++k) pp[r][k] += __shfl_xor(pp[r][k], m);

  float4 bp4 = *(const float4*)bpool;
  float bp[4] = {bp4.x, bp4.y, bp4.z, bp4.w};
  float sv[4][4];
#pragma unroll
  for (int r = 0; r < 4; ++r) {
    float p[4];
#pragma unroll
    for (int k = 0; k < 4; ++k) p[k] = pp[r][k] + bp[k];
    float mx = fmaxf(fmaxf(p[0], p[1]), fmaxf(p[2], p[3]));
    float e0 = expf(p[0] - mx), e1 = expf(p[1] - mx), e2 = expf(p[2] - mx), e3 = expf(p[3] - mx);
    float inv = 1.f / (e0 + e1 + e2 + e3);
    float valid = (g4 * 4 + r < nrows) ? 1.f : 0.f;
    sv[r][0] = e0 * inv * valid; sv[r][1] = e1 * inv * valid;
    sv[r][2] = e2 * inv * valid; sv[r][3] = e3 * inv * valid;
  }

  // write s
  {
    int rW = li >> 2, kW = li & 3;
    if (g4 * 4 + rW < nrows) {
      int node = node0 + g4 * 4 + rW;
      float val = 0.f;
#pragma unroll
      for (int rr = 0; rr < 4; ++rr)
#pragma unroll
        for (int kk = 0; kk < 4; ++kk)
          if (li == rr * 4 + kk) val = sv[rr][kk];
      s_out[node * 4 + kW] = val;
    }
  }

  // ss[b][k1][k2]
  {
    int k1 = li >> 2, k2 = li & 3;
    float a1[4], a2[4];
#pragma unroll
    for (int rr = 0; rr < 4; ++rr) {
      float v1 = 0.f, v2 = 0.f;
#pragma unroll
      for (int kk = 0; kk < 4; ++kk) {
        if (k1 == kk) v1 = sv[rr][kk];
        if (k2 == kk) v2 = sv[rr][kk];
      }
      a1[rr] = v1; a2[rr] = v2;
    }
    float ssv = a1[0] * a2[0] + a1[1] * a2[1] + a1[2] * a2[2] + a1[3] * a2[3];
    atomicAdd(&ssL[li], ssv);
  }

  // den += deg * ||s||^2
  if (li == 0) {
    float dent = 0.f;
#pragma unroll
    for (int rr = 0; rr < 4; ++rr) {
      int rowg = g4 * 4 + rr;
      if (rowg < nrows) {
        float dg = (float)count[node0 + rowg];
        dent += dg * (sv[rr][0] * sv[rr][0] + sv[rr][1] * sv[rr][1] +
                      sv[rr][2] * sv[rr][2] + sv[rr][3] * sv[rr][3]);
      }
    }
    atomicAdd(&denL, dent);
  }

  // out[k][c] += s[r][k]*h[r][c]
  float po[4][8];
#pragma unroll
  for (int k = 0; k < 4; ++k)
#pragma unroll
    for (int c = 0; c < 8; ++c) po[k][c] = 0.f;
#pragma unroll
  for (int k = 0; k < 4; ++k)
#pragma unroll
    for (int rr = 0; rr < 4; ++rr)
#pragma unroll
      for (int c = 0; c < 8; ++c) po[k][c] = fmaf(sv[rr][k], h[rr][c], po[k][c]);
#pragma unroll
  for (int k = 0; k < 4; ++k)
#pragma unroll
    for (int c = 0; c < 8; ++c) {
      po[k][c] += __shfl_xor(po[k][c], 16);
      po[k][c] += __shfl_xor(po[k][c], 32);
    }
  if ((t & 63) < 16) {
#pragma unroll
    for (int k = 0; k < 4; ++k)
#pragma unroll
      for (int c = 0; c < 8; ++c)
        atomicAdd(&outL[k][c0 + (c & 3) + (c >> 2) * 64], po[k][c]);
  }

  __syncthreads();
  for (int i = t; i < KC * HID; i += 256)
    atomicAdd(&out_pool[bG * KC * HID + i], ((const float*)outL)[i]);
  if (t < 16) atomicAdd(&ss_g[bG * 16 + t], ssL[t]);
  if (t == 0) atomicAdd(&den_g[bG], denL);
}

// ---------------------------------------------------------------- K4: out_adj — masked 8-wide batches (no serial remainder)
__global__ __launch_bounds__(256) void k_adj2(const int* __restrict__ count,
                                              const int* __restrict__ rowptr,
                                              const int* __restrict__ csr,
                                              const float* __restrict__ s,
                                              const float* __restrict__ zf,
                                              float* __restrict__ adjraw) {
  __shared__ float accL[4][2][16];  // [wave][graph-within-block][k1*4+k2]
  const int t = threadIdx.x;
  if (t < 128) ((float*)accL)[t] = 0.f;
  __syncthreads();
  const int node = blockIdx.x * 256 + t;
  const int g0 = (blockIdx.x * 256) / BLK;
  if (node < NN) {
    const int gi = node / BLK - g0;  // 0 or 1
    const int deg = count[node];
    const int* sl = csr + rowptr[node];
    float a[8][4];
#pragma unroll
    for (int q = 0; q < 8; ++q)
#pragma unroll
      for (int c = 0; c < 4; ++c) a[q][c] = 0.f;
    const int nb8 = (deg + 7) >> 3;
    for (int b = 0; b < nb8; ++b) {
      const float* p[8];
#pragma unroll
      for (int q = 0; q < 8; ++q) {
        int ee = b * 8 + q;
        int si = (ee < deg) ? sl[ee] : 0;
        p[q] = (ee < deg) ? (s + (size_t)si * 4) : zf;
      }
      float4 v[8];
#pragma unroll
      for (int q = 0; q < 8; ++q) v[q] = *(const float4*)p[q];
#pragma unroll
      for (int q = 0; q < 8; ++q) {
        a[q][0] += v[q].x; a[q][1] += v[q].y; a[q][2] += v[q].z; a[q][3] += v[q].w;
      }
    }
    float t0 = 0.f, t1 = 0.f, t2 = 0.f, t3 = 0.f;
#pragma unroll
    for (int q = 0; q < 8; ++q) { t0 += a[q][0]; t1 += a[q][1]; t2 += a[q][2]; t3 += a[q][3]; }
    float4 sn = *(const float4*)(s + (size_t)node * 4);
    float* base = accL[t >> 6][gi];
#pragma unroll
    for (int i = 0; i < 16; ++i) {
      int idx = (i + t) & 15;  // stagger: 4-way instead of 64-way contention
      int hi = idx >> 2, lo = idx & 3;
      float a1 = (hi == 0) ? sn.x : (hi == 1) ? sn.y : (hi == 2) ? sn.z : sn.w;
      float b1 = (lo == 0) ? t0 : (lo == 1) ? t1 : (lo == 2) ? t2 : t3;
      atomicAdd(base + idx, a1 * b1);
    }
  }
  __syncthreads();
  if (t < 32) {
    int gi = t >> 4, i = t & 15, gg = g0 + gi;
    if (gg < NB) {
      float v = accL[0][gi][i] + accL[1][gi][i] + accL[2][gi][i] + accL[3][gi][i];
      atomicAdd(&adjraw[gg * 16 + i], v);
    }
  }
}

// ---------------------------------------------------------------- K5a: per-graph tail
__global__ __launch_bounds__(128) void k_graph(
    const float* __restrict__ out_pool, const float* __restrict__ adjraw,
    const float* __restrict__ den_g, const float* __restrict__ ss_g,
    const float* __restrict__ Wrel3, const float* __restrict__ brel3,
    const float* __restrict__ Wroot3, const float* __restrict__ Wlin1,
    const float* __restrict__ blin1, const float* __restrict__ Wlin2,
    const float* __restrict__ blin2, float* __restrict__ d_out,
    float* __restrict__ scratch) {
  const int b = blockIdx.x, t = threadIdx.x;
  __shared__ float adjL[16], adjnL[16], dL[4];
  __shared__ float osL[128], msL[128], x2mL[128], x3L[128];
  if (t < 16) adjL[t] = adjraw[b * 16 + t];
  __syncthreads();
  if (t < 4) {
    float srow = 0.f;
#pragma unroll
    for (int l = 0; l < 4; ++l)
      if (l != t) srow += adjL[t * 4 + l];
    dL[t] = sqrtf(srow) + 1e-15f;
  }
  __syncthreads();
  if (t < 16) {
    int k1 = t >> 2, k2 = t & 3;
    float az = (k1 == k2) ? 0.f : adjL[t];
    float an = az / (dL[k2] * dL[k1]);
    adjnL[t] = an;
    d_out[400018 + b * 16 + t] = an;
  }
  __syncthreads();
  float o0 = out_pool[b * 512 + 0 * 128 + t];
  float o1 = out_pool[b * 512 + 1 * 128 + t];
  float o2 = out_pool[b * 512 + 2 * 128 + t];
  float o3 = out_pool[b * 512 + 3 * 128 + t];
  float m0 = adjnL[0] * o0 + adjnL[1] * o1 + adjnL[2] * o2 + adjnL[3] * o3;
  float m1 = adjnL[4] * o0 + adjnL[5] * o1 + adjnL[6] * o2 + adjnL[7] * o3;
  float m2 = adjnL[8] * o0 + adjnL[9] * o1 + adjnL[10] * o2 + adjnL[11] * o3;
  float m3 = adjnL[12] * o0 + adjnL[13] * o1 + adjnL[14] * o2 + adjnL[15] * o3;
  osL[t] = o0 + o1 + o2 + o3;
  msL[t] = m0 + m1 + m2 + m3;
  __syncthreads();
  float accc = brel3[t];
  for (int j = 0; j < 128; ++j)
    accc += 0.25f * (msL[j] * Wrel3[j * 128 + t] + osL[j] * Wroot3[j * 128 + t]);
  x2mL[t] = accc;
  __syncthreads();
  float a2 = blin1[t];
  for (int j = 0; j < 128; ++j) a2 += x2mL[j] * Wlin1[j * 128 + t];
  x3L[t] = fmaxf(a2, 0.f);
  __syncthreads();
  if (t < 2) {
    float lg = blin2[t];
    for (int j = 0; j < 128; ++j) lg += x3L[j] * Wlin2[j * 2 + t];
    scratch[b * 2 + t] = lg;
  }
  if (t == 0) {
    float tr = adjL[0] + adjL[5] + adjL[10] + adjL[15];
    scratch[16 + b] = tr / den_g[b];
    float n2 = 0.f;
    for (int i = 0; i < 16; ++i) { float v = ss_g[b * 16 + i]; n2 += v * v; }
    float nn = sqrtf(n2);
    float od = 0.f;
    for (int i = 0; i < 16; ++i) {
      float v = ss_g[b * 16 + i] / nn - (((i >> 2) == (i & 3)) ? 0.5f : 0.f);
      od += v * v;
    }
    scratch[24 + b] = sqrtf(od);
  }
}

// ---------------------------------------------------------------- K5b: losses + log_softmax
__global__ void k_final(const float* __restrict__ scratch, float* __restrict__ d_out) {
  if (threadIdx.x == 0 && blockIdx.x == 0) {
    float mc = 0.f, oo = 0.f;
    for (int b = 0; b < NB; ++b) { mc += scratch[16 + b]; oo += scratch[24 + b]; }
    d_out[16] = -(mc / (float)NB);
    d_out[17] = oo / (float)NB;
    for (int b = 0; b < NB; ++b) {
      float l0 = scratch[2 * b], l1 = scratch[2 * b + 1];
      float m = fmaxf(l0, l1);
      float lse = m + logf(expf(l0 - m) + expf(l1 - m));
      d_out[2 * b] = l0 - lse;
      d_out[2 * b + 1] = l1 - lse;
    }
  }
}

// ---------------------------------------------------------------- launch
extern "C" void kernel_launch(void* const* d_in, const int* in_sizes, int n_in,
                              void* d_out, int out_size, void* d_ws, size_t ws_size,
                              hipStream_t stream) {
  (void)in_sizes; (void)n_in; (void)out_size; (void)ws_size;
  const float* x      = (const float*)d_in[0];
  const int*   ei     = (const int*)d_in[1];
  const float* Wroot1 = (const float*)d_in[3];
  const float* Wrel1  = (const float*)d_in[4];
  const float* brel1  = (const float*)d_in[5];
  const float* Wpool  = (const float*)d_in[6];
  const float* bpool  = (const float*)d_in[7];
  const float* Wrel3  = (const float*)d_in[8];
  const float* brel3  = (const float*)d_in[9];
  const float* Wroot3 = (const float*)d_in[10];
  const float* Wlin1  = (const float*)d_in[11];
  const float* blin1  = (const float*)d_in[12];
  const float* Wlin2  = (const float*)d_in[13];
  const float* blin2  = (const float*)d_in[14];
  float* out = (float*)d_out;

  char* ws = (char*)d_ws;
  float*  out_pool = (float*)(ws + 0);          //  16384 B (memset)
  float*  ss_g     = (float*)(ws + 16384);      //    512 B (memset)
  float*  adjraw   = (float*)(ws + 16896);      //    512 B (memset)
  float*  den_g    = (float*)(ws + 17408);      //     32 B (memset)
  float*  scratch  = (float*)(ws + 17440);      //    128 B (memset)
  int*    sbcnt    = (int*)(ws + 17568);        //   1568 B (memset)
  ushort* zrow     = (ushort*)(ws + 19136);     //    256 B zeros (memset)
  float*  zf       = (float*)(ws + 19392);      //     16 B zeros (memset)
  int*    sbbase   = (int*)(ws + 19648);        //   1600 B
  int*    count    = (int*)(ws + 21248);        // 400000 B
  int*    rowptr   = (int*)(ws + 421248);       // 400016 B
  ushort* Wt       = (ushort*)(ws + 821264);    //  65536 B [128][256]
  int*    csr      = (int*)(ws + 886800);       // 6400000 B [E]
  ushort* xb       = (ushort*)(ws + 7286800);   // 25600000 B [N][128] bf16
  ushort* aggb     = (ushort*)(ws + 32886800);  // 25600000 B [N][128] bf16
  uint*   gbuf     = (uint*)(ws + 58486800);    // 8028160 B
  ushort* hbuf     = (ushort*)(ws + 66514960);  // 25600000 B [N][128] bf16

  hipMemsetAsync(ws, 0, 19648, stream);
  k_prep_x<<<12500, 256, 0, stream>>>((const float4*)x, xb);
  k_prep_w<<<128, 256, 0, stream>>>(Wrel1, Wroot1, Wt);
  k_bucket2<<<196, 256, 0, stream>>>(ei, sbcnt, gbuf);
  k_scan392<<<1, 512, 0, stream>>>(sbcnt, sbbase);
  k_csr_tile<<<NBIN, 256, 0, stream>>>(gbuf, sbcnt, sbbase, rowptr, count, csr);
  k_agg2<<<8 * ((BLK + 7) / 8), 256, 0, stream>>>(xb, count, rowptr, csr, zrow, aggb);
  k_gemm<<<NB * CHUNKS, 256, 0, stream>>>(aggb, xb, Wt, brel1, hbuf);
  k_epi<<<NB * CHUNKS, 256, 0, stream>>>(hbuf, Wpool, bpool, count, out + 18,
                                         out_pool, ss_g, den_g);
  k_adj2<<<(NN + 255) / 256, 256, 0, stream>>>(count, rowptr, csr, out + 18, zf, adjraw);
  k_graph<<<NB, 128, 0, stream>>>(out_pool, adjraw, den_g, ss_g, Wrel3, brel3, Wroot3,
                                  Wlin1, blin1, Wlin2, blin2, out, scratch);
  k_final<<<1, 64, 0, stream>>>(scratch, out);
}

// Round 19
// 202.595 us; speedup vs baseline: 1.1944x; 1.0197x over previous
//
#include <hip/hip_runtime.h>

// Problem constants (fixed by the reference)
#define NN     100000      // nodes
#define EE     1600000     // edges
#define NB     8           // graphs
#define BLK    12500       // nodes per graph
#define HID    128
#define KC     4
#define CHUNKS 196         // ceil(12500/64)
#define NTILE  49          // dst-ranges of 256 nodes per graph
#define NBIN   392         // 8 graphs x 49 tiles
#define GCAPS  5120        // per-bin capacity (mean 4081, sigma ~64)

typedef __attribute__((ext_vector_type(8))) short bf16x8;
typedef __attribute__((ext_vector_type(4))) float f32x4;

__device__ __forceinline__ ushort f2bf(float f) {
  uint u = __float_as_uint(f);
  return (ushort)((u + 0x7FFFu + ((u >> 16) & 1u)) >> 16);  // RNE
}
__device__ __forceinline__ float bf2f(ushort h) {
  return __uint_as_float(((uint)h) << 16);
}

#define GLL16(g, l) \
  __builtin_amdgcn_global_load_lds((const __attribute__((address_space(1))) void*)(g), \
                                   (__attribute__((address_space(3))) void*)(l), 16, 0, 0)

// ---------------------------------------------------------------- K0: x->bf16 + Wt transpose + control-region zero (3 dispatches merged)
__global__ __launch_bounds__(256) void k_prep(const float4* __restrict__ x4,
                                              ushort* __restrict__ xb,
                                              const float* __restrict__ Wrel1,
                                              const float* __restrict__ Wroot1,
                                              ushort* __restrict__ Wt,
                                              uint* __restrict__ zbase) {
  const int bi = blockIdx.x;
  const int t = threadIdx.x;
  if (bi < 12500) {
    int i = bi * 256 + t;  // 3.2M float4s exactly
    float4 v = x4[i];
    ushort4 r;
    r.x = f2bf(v.x); r.y = f2bf(v.y); r.z = f2bf(v.z); r.w = f2bf(v.w);
    *(ushort4*)(xb + (size_t)i * 4) = r;
  } else if (bi < 12628) {
    int col = bi - 12500, k = t;
    float v = (k < 128) ? Wrel1[k * 128 + col] : Wroot1[(k - 128) * 128 + col];
    Wt[col * 256 + k] = f2bf(v);
  } else {
    // zero 19648 B control region (4912 dwords)
    for (int i = t; i < 4912; i += 256) zbase[i] = 0u;
  }
}

// ---------------------------------------------------------------- K1a: edges -> 392 (graph, dst-range) sub-buckets
__global__ __launch_bounds__(256) void k_bucket2(const int* __restrict__ ei,
                                                 int* __restrict__ sbcnt,
                                                 uint* __restrict__ gbuf) {
  __shared__ uint stage[8192];
  __shared__ int cnt[NBIN], start[NBIN + 1], rbase[NBIN];
  __shared__ int gtot[8], gb[8];
  const int t = threadIdx.x;
  for (int b = t; b < NBIN; b += 256) cnt[b] = 0;
  __syncthreads();
  const int e0 = blockIdx.x * 8192;
  uint pk[32]; int br[32];
#pragma unroll
  for (int i = 0; i < 32; ++i) {
    int e = e0 + i * 256 + t;
    bool val = (e < EE);
    int src = 0, dst = 0;
    if (val) {
      src = __builtin_nontemporal_load(ei + e);
      dst = __builtin_nontemporal_load(ei + EE + e);
    }
    int g = dst / BLK;
    int dl = dst - g * BLK;
    int sl = src - g * BLK;
    int bin = g * NTILE + (dl >> 8);
    pk[i] = ((uint)sl << 16) | (uint)dl;
    br[i] = val ? ((bin << 14) | atomicAdd(&cnt[bin], 1)) : -1;
  }
  __syncthreads();
  if (t < 8) {
    int s = 0;
    for (int k = 0; k < NTILE; ++k) s += cnt[t * NTILE + k];
    gtot[t] = s;
  }
  __syncthreads();
  if (t == 0) {
    int s = 0;
    for (int g = 0; g < 8; ++g) { gb[g] = s; s += gtot[g]; }
    start[NBIN] = s;
  }
  __syncthreads();
  if (t < 8) {
    int run = gb[t];
    for (int k = 0; k < NTILE; ++k) { start[t * NTILE + k] = run; run += cnt[t * NTILE + k]; }
  }
  __syncthreads();
  for (int b = t; b < NBIN; b += 256) rbase[b] = atomicAdd(&sbcnt[b], cnt[b]);
#pragma unroll
  for (int i = 0; i < 32; ++i) {
    if (br[i] >= 0) {
      int bin = br[i] >> 14, rank = br[i] & 16383;
      stage[start[bin] + rank] = pk[i];
    }
  }
  __syncthreads();
  // per-bin segmented flush
  for (int b = t; b < NBIN; b += 256) {
    const int n = cnt[b];
    const int s0 = start[b];
    uint* dst = gbuf + (size_t)b * GCAPS + rbase[b];
    for (int i = 0; i < n; ++i) dst[i] = stage[s0 + i];
  }
}

// ---------------------------------------------------------------- K1b: per-bin LDS counting sort -> dense CSR (scan inlined)
__global__ __launch_bounds__(256) void k_csr_tile(const uint* __restrict__ gbuf,
                                                  const int* __restrict__ sbcnt,
                                                  int* __restrict__ rowptr,
                                                  int* __restrict__ count,
                                                  int* __restrict__ csr) {
  const int g = blockIdx.x & 7;     // XCD-local per graph
  const int tile = blockIdx.x >> 3; // 0..48
  const int bin = g * NTILE + tile;
  const int m = sbcnt[bin];
  const int n0t = tile * 256;
  const int nt = min(256, BLK - n0t);
  __shared__ uint ent[GCAPS];
  __shared__ ushort srt[GCAPS];
  __shared__ int cnt[256], scn[256], cur[256];
  __shared__ int red[256];
  const int t = threadIdx.x;
  // inline exclusive-scan base = sum(sbcnt[0..bin))
  {
    int partial = 0;
    for (int i = t; i < bin; i += 256) partial += sbcnt[i];
    red[t] = partial;
    __syncthreads();
    for (int off = 128; off > 0; off >>= 1) {
      if (t < off) red[t] += red[t + off];
      __syncthreads();
    }
  }
  const int base = red[0];
  cnt[t] = 0;
  __syncthreads();
  const uint* buf = gbuf + (size_t)bin * GCAPS;
  for (int i = t; i < m; i += 256) {
    uint pk = buf[i];
    ent[i] = pk;
    atomicAdd(&cnt[(int)(pk & 0xFFFFu) - n0t], 1);
  }
  __syncthreads();
  int v = cnt[t];
  scn[t] = v;
  __syncthreads();
  for (int s = 1; s < 256; s <<= 1) {
    int x = (t >= s) ? scn[t - s] : 0;
    __syncthreads();
    scn[t] += x;
    __syncthreads();
  }
  int excl = scn[t] - v;
  cur[t] = excl;
  if (t < nt) {
    rowptr[g * BLK + n0t + t] = base + excl;
    count[g * BLK + n0t + t] = v;
  }
  __syncthreads();
  for (int i = t; i < m; i += 256) {
    uint pk = ent[i];
    int p = atomicAdd(&cur[(int)(pk & 0xFFFFu) - n0t], 1);
    srt[p] = (ushort)(pk >> 16);
  }
  __syncthreads();
  const int nb = g * BLK;
  for (int i = t; i < m; i += 256)
    csr[base + i] = nb + (int)srt[i];  // dense coalesced
}

// ---------------------------------------------------------------- K2: agg[n] = sum_{e: dst=n} x[src]  (R18 structure, best measured)
__global__ __launch_bounds__(256) void k_agg2(const ushort* __restrict__ xb,
                                              const int* __restrict__ count,
                                              const int* __restrict__ rowptr,
                                              const int* __restrict__ csr,
                                              const ushort* __restrict__ zrow,
                                              ushort* __restrict__ aggb) {
  const int xg = blockIdx.x & 7;
  const int j = blockIdx.x >> 3;
  const int half = threadIdx.x >> 5;  // 8 half-waves = 8 nodes per block
  const int lane = threadIdx.x & 31;
  const int ln = j * 8 + half;
  if (ln >= BLK) return;
  const int node = xg * BLK + ln;
  const int deg = count[node];
  const int* sl = csr + rowptr[node];
  int idx0 = (lane < deg) ? sl[lane] : 0;
  int idx1 = (32 + lane < deg) ? sl[32 + lane] : 0;
  const ushort* zr = zrow + lane * 4;

  float4 acc[8];
#pragma unroll
  for (int q = 0; q < 8; ++q) acc[q] = (float4){0.f, 0.f, 0.f, 0.f};

  const int nb8 = (deg + 7) >> 3;
  for (int b = 0; b < nb8; ++b) {
    const int e = b * 8;
    const ushort* ps[8];
#pragma unroll
    for (int q = 0; q < 8; ++q) {
      int ee = e + q;
      int si = (ee < 32) ? __shfl(idx0, ee, 32)
             : ((ee < 64) ? __shfl(idx1, ee - 32, 32)
                          : ((ee < deg) ? sl[ee] : 0));
      ps[q] = (ee < deg) ? (xb + (size_t)si * HID + lane * 4) : zr;
    }
    uint2 v[8];
#pragma unroll
    for (int q = 0; q < 8; ++q) v[q] = *(const uint2*)ps[q];
#pragma unroll
    for (int q = 0; q < 8; ++q) {
      acc[q].x += __uint_as_float(v[q].x << 16);
      acc[q].y += __uint_as_float(v[q].x & 0xFFFF0000u);
      acc[q].z += __uint_as_float(v[q].y << 16);
      acc[q].w += __uint_as_float(v[q].y & 0xFFFF0000u);
    }
  }

  float lo0 = 0.f, hi0 = 0.f, lo1 = 0.f, hi1 = 0.f;
#pragma unroll
  for (int q = 0; q < 8; ++q) { lo0 += acc[q].x; hi0 += acc[q].y; lo1 += acc[q].z; hi1 += acc[q].w; }
  ushort4 r;
  r.x = f2bf(lo0); r.y = f2bf(hi0); r.z = f2bf(lo1); r.w = f2bf(hi1);
  *(ushort4*)(aggb + (size_t)node * HID + lane * 4) = r;
}

// ---------------------------------------------------------------- K3a: GEMM half — stage A (DMA) + MFMA + bias/relu -> hbuf (dense bf16)
__global__ __launch_bounds__(256) void k_gemm(
    const ushort* __restrict__ aggb, const ushort* __restrict__ xb,
    const ushort* __restrict__ Wt, const float* __restrict__ brel1,
    ushort* __restrict__ hbuf) {
  __shared__ ushort Aag_s[64][128];  // 16 KB, linear (DMA dest)
  __shared__ ushort Ax_s[64][128];   // 16 KB, linear (DMA dest)
  __shared__ ushort hLb[64][136];    // h tile bf16 (pad 136)

  const int t = threadIdx.x;
  const int bi = blockIdx.x;
  const int bG = bi & 7;
  const int chunk = bi >> 3;
  const int node0 = bG * BLK + chunk * 64;
  int nrows = BLK - chunk * 64;
  if (nrows > 64) nrows = 64;

  const int w = t >> 6;
  const int l = t & 63;

  // async stage: 8 global_load_lds per wave (4 agg + 4 x tiles)
  {
    const int sub = l >> 4;
    const int c16 = l & 15;
#pragma unroll
    for (int i = 0; i < 4; ++i) {
      const int j = w * 4 + i;
      const int row = j * 4 + sub;
      const int rs = (row < nrows) ? row : (nrows - 1);
      const int boff = (c16 * 16) ^ ((row & 7) << 4);
      const ushort* ga = aggb + (size_t)(node0 + rs) * HID + (boff >> 1);
      const ushort* gx = xb + (size_t)(node0 + rs) * HID + (boff >> 1);
      GLL16(ga, &Aag_s[j * 4][0]);
      GLL16(gx, &Ax_s[j * 4][0]);
    }
  }

  const int m16 = l & 15;
  const int gq = l >> 4;

  bf16x8 Breg[8][2];
#pragma unroll
  for (int kt = 0; kt < 8; ++kt)
#pragma unroll
    for (int fc = 0; fc < 2; ++fc)
      Breg[kt][fc] =
          *(const bf16x8*)(Wt + (size_t)(32 * w + 16 * fc + m16) * 256 + kt * 32 + 8 * gq);

  f32x4 acc[4][2];
#pragma unroll
  for (int fr = 0; fr < 4; ++fr)
#pragma unroll
    for (int fc = 0; fc < 2; ++fc) acc[fr][fc] = (f32x4){0.f, 0.f, 0.f, 0.f};

  asm volatile("s_waitcnt vmcnt(0)" ::: "memory");
  __syncthreads();

#pragma unroll
  for (int kt = 0; kt < 8; ++kt) {
    const int k4 = kt & 3;
    bf16x8 af[4];
#pragma unroll
    for (int fr = 0; fr < 4; ++fr) {
      const int r = 16 * fr + m16;
      const int ci = (k4 * 32 + gq * 8) ^ ((r & 7) << 3);
      af[fr] = (kt < 4) ? *(const bf16x8*)&Aag_s[r][ci]
                        : *(const bf16x8*)&Ax_s[r][ci];
    }
#pragma unroll
    for (int fr = 0; fr < 4; ++fr)
#pragma unroll
      for (int fc = 0; fc < 2; ++fc)
        acc[fr][fc] = __builtin_amdgcn_mfma_f32_16x16x32_bf16(af[fr], Breg[kt][fc],
                                                              acc[fr][fc], 0, 0, 0);
  }

  const float bc0 = brel1[32 * w + m16];
  const float bc1 = brel1[32 * w + 16 + m16];
#pragma unroll
  for (int fr = 0; fr < 4; ++fr)
#pragma unroll
    for (int fc = 0; fc < 2; ++fc)
#pragma unroll
      for (int r = 0; r < 4; ++r)
        hLb[16 * fr + 4 * gq + r][32 * w + 16 * fc + m16] =
            f2bf(fmaxf(acc[fr][fc][r] + (fc ? bc1 : bc0), 0.f));
  __syncthreads();

  // dense h store: thread t -> row t>>2, 64 B chunk (t&3)
  {
    const int row = t >> 2;
    const int ch = (t & 3) * 32;
    if (row < nrows) {
      ushort* dst = hbuf + (size_t)(node0 + row) * HID + ch;
      const ushort* src = &hLb[row][ch];
#pragma unroll
      for (int q = 0; q < 4; ++q)
        *(bf16x8*)(dst + q * 8) = *(const bf16x8*)(src + q * 8);
    }
  }
}

// ---------------------------------------------------------------- K3b: epilogue half — read h, softmax + pooled reductions
__global__ __launch_bounds__(256) void k_epi(
    const ushort* __restrict__ hbuf, const float* __restrict__ Wpool,
    const float* __restrict__ bpool, const int* __restrict__ count,
    float* __restrict__ s_out, float* __restrict__ out_pool,
    float* __restrict__ ss_g, float* __restrict__ den_g) {
  __shared__ ushort hLb[64][136];
  __shared__ float outL[KC][HID];
  __shared__ float ssL[16];
  __shared__ float denL;

  const int t = threadIdx.x;
  const int bi = blockIdx.x;
  const int bG = bi & 7;
  const int chunk = bi >> 3;
  const int node0 = bG * BLK + chunk * 64;
  int nrows = BLK - chunk * 64;
  if (nrows > 64) nrows = 64;

  // dense h load: thread t -> row t>>2, 64 B chunk (t&3)
  {
    const int row = t >> 2;
    const int ch = (t & 3) * 32;
    const int rs = (row < nrows) ? row : (nrows - 1);
    const ushort* src = hbuf + (size_t)(node0 + rs) * HID + ch;
    ushort* dst = &hLb[row][ch];
#pragma unroll
    for (int q = 0; q < 4; ++q)
      *(bf16x8*)(dst + q * 8) = *(const bf16x8*)(src + q * 8);
  }

  for (int i = t; i < KC * HID; i += 256) ((float*)outL)[i] = 0.f;
  if (t < 16) ssL[t] = 0.f;
  if (t == 0) denL = 0.f;
  __syncthreads();

  const int g4 = t >> 4;
  const int c0 = (t & 15) << 2;
  const int li = t & 15;

  float h[4][8];
#pragma unroll
  for (int r = 0; r < 4; ++r) {
    ushort4 v0 = *(const ushort4*)&hLb[g4 * 4 + r][c0];
    ushort4 v1 = *(const ushort4*)&hLb[g4 * 4 + r][c0 + 64];
    h[r][0] = bf2f(v0.x); h[r][1] = bf2f(v0.y); h[r][2] = bf2f(v0.z); h[r][3] = bf2f(v0.w);
    h[r][4] = bf2f(v1.x); h[r][5] = bf2f(v1.y); h[r][6] = bf2f(v1.z); h[r][7] = bf2f(v1.w);
  }

  // pooling head: p = h @ Wpool
  float wp[8][4];
#pragma unroll
  for (int j = 0; j < 8; ++j) {
    int col = c0 + (j & 3) + (j >> 2) * 64;
    float4 v = *(const float4*)(Wpool + col * 4);
    wp[j][0] = v.x; wp[j][1] = v.y; wp[j][2] = v.z; wp[j][3] = v.w;
  }
  float pp[4][4];
#pragma unroll
  for (int r = 0; r < 4; ++r)
#pragma unroll
    for (int k = 0; k < 4; ++k) pp[r][k] = 0.f;
#pragma unroll
  for (int r = 0; r < 4; ++r)
#pragma unroll
    for (int j = 0; j < 8; ++j)
#pragma unroll
      for (int k = 0; k < 4; ++k) pp[r][k] = fmaf(h[r][j], wp[j][k], pp[r][k]);
#pragma unroll
  for (int m = 1; m <= 8; m <<= 1)
#pragma unroll
    for (int r = 0; r < 4; ++r)
#pragma unroll
      for (int k = 0; k < 4; ++k) pp[r][k] += __shfl_xor(pp[r][k], m);

  float4 bp4 = *(const float4*)bpool;
  float bp[4] = {bp4.x, bp4.y, bp4.z, bp4.w};
  float sv[4][4];
#pragma unroll
  for (int r = 0; r < 4; ++r) {
    float p[4];
#pragma unroll
    for (int k = 0; k < 4; ++k) p[k] = pp[r][k] + bp[k];
    float mx = fmaxf(fmaxf(p[0], p[1]), fmaxf(p[2], p[3]));
    float e0 = expf(p[0] - mx), e1 = expf(p[1] - mx), e2 = expf(p[2] - mx), e3 = expf(p[3] - mx);
    float inv = 1.f / (e0 + e1 + e2 + e3);
    float valid = (g4 * 4 + r < nrows) ? 1.f : 0.f;
    sv[r][0] = e0 * inv * valid; sv[r][1] = e1 * inv * valid;
    sv[r][2] = e2 * inv * valid; sv[r][3] = e3 * inv * valid;
  }

  // write s
  {
    int rW = li >> 2, kW = li & 3;
    if (g4 * 4 + rW < nrows) {
      int node = node0 + g4 * 4 + rW;
      float val = 0.f;
#pragma unroll
      for (int rr = 0; rr < 4; ++rr)
#pragma unroll
        for (int kk = 0; kk < 4; ++kk)
          if (li == rr * 4 + kk) val = sv[rr][kk];
      s_out[node * 4 + kW] = val;
    }
  }

  // ss[b][k1][k2]
  {
    int k1 = li >> 2, k2 = li & 3;
    float a1[4], a2[4];
#pragma unroll
    for (int rr = 0; rr < 4; ++rr) {
      float v1 = 0.f, v2 = 0.f;
#pragma unroll
      for (int kk = 0; kk < 4; ++kk) {
        if (k1 == kk) v1 = sv[rr][kk];
        if (k2 == kk) v2 = sv[rr][kk];
      }
      a1[rr] = v1; a2[rr] = v2;
    }
    float ssv = a1[0] * a2[0] + a1[1] * a2[1] + a1[2] * a2[2] + a1[3] * a2[3];
    atomicAdd(&ssL[li], ssv);
  }

  // den += deg * ||s||^2
  if (li == 0) {
    float dent = 0.f;
#pragma unroll
    for (int rr = 0; rr < 4; ++rr) {
      int rowg = g4 * 4 + rr;
      if (rowg < nrows) {
        float dg = (float)count[node0 + rowg];
        dent += dg * (sv[rr][0] * sv[rr][0] + sv[rr][1] * sv[rr][1] +
                      sv[rr][2] * sv[rr][2] + sv[rr][3] * sv[rr][3]);
      }
    }
    atomicAdd(&denL, dent);
  }

  // out[k][c] += s[r][k]*h[r][c]
  float po[4][8];
#pragma unroll
  for (int k = 0; k < 4; ++k)
#pragma unroll
    for (int c = 0; c < 8; ++c) po[k][c] = 0.f;
#pragma unroll
  for (int k = 0; k < 4; ++k)
#pragma unroll
    for (int rr = 0; rr < 4; ++rr)
#pragma unroll
      for (int c = 0; c < 8; ++c) po[k][c] = fmaf(sv[rr][k], h[rr][c], po[k][c]);
#pragma unroll
  for (int k = 0; k < 4; ++k)
#pragma unroll
    for (int c = 0; c < 8; ++c) {
      po[k][c] += __shfl_xor(po[k][c], 16);
      po[k][c] += __shfl_xor(po[k][c], 32);
    }
  if ((t & 63) < 16) {
#pragma unroll
    for (int k = 0; k < 4; ++k)
#pragma unroll
      for (int c = 0; c < 8; ++c)
        atomicAdd(&outL[k][c0 + (c & 3) + (c >> 2) * 64], po[k][c]);
  }

  __syncthreads();
  for (int i = t; i < KC * HID; i += 256)
    atomicAdd(&out_pool[bG * KC * HID + i], ((const float*)outL)[i]);
  if (t < 16) atomicAdd(&ss_g[bG * 16 + t], ssL[t]);
  if (t == 0) atomicAdd(&den_g[bG], denL);
}

// ---------------------------------------------------------------- K4: out_adj — masked 8-wide batches (no serial remainder)
__global__ __launch_bounds__(256) void k_adj2(const int* __restrict__ count,
                                              const int* __restrict__ rowptr,
                                              const int* __restrict__ csr,
                                              const float* __restrict__ s,
                                              const float* __restrict__ zf,
                                              float* __restrict__ adjraw) {
  __shared__ float accL[4][2][16];  // [wave][graph-within-block][k1*4+k2]
  const int t = threadIdx.x;
  if (t < 128) ((float*)accL)[t] = 0.f;
  __syncthreads();
  const int node = blockIdx.x * 256 + t;
  const int g0 = (blockIdx.x * 256) / BLK;
  if (node < NN) {
    const int gi = node / BLK - g0;  // 0 or 1
    const int deg = count[node];
    const int* sl = csr + rowptr[node];
    float a[8][4];
#pragma unroll
    for (int q = 0; q < 8; ++q)
#pragma unroll
      for (int c = 0; c < 4; ++c) a[q][c] = 0.f;
    const int nb8 = (deg + 7) >> 3;
    for (int b = 0; b < nb8; ++b) {
      const float* p[8];
#pragma unroll
      for (int q = 0; q < 8; ++q) {
        int ee = b * 8 + q;
        int si = (ee < deg) ? sl[ee] : 0;
        p[q] = (ee < deg) ? (s + (size_t)si * 4) : zf;
      }
      float4 v[8];
#pragma unroll
      for (int q = 0; q < 8; ++q) v[q] = *(const float4*)p[q];
#pragma unroll
      for (int q = 0; q < 8; ++q) {
        a[q][0] += v[q].x; a[q][1] += v[q].y; a[q][2] += v[q].z; a[q][3] += v[q].w;
      }
    }
    float t0 = 0.f, t1 = 0.f, t2 = 0.f, t3 = 0.f;
#pragma unroll
    for (int q = 0; q < 8; ++q) { t0 += a[q][0]; t1 += a[q][1]; t2 += a[q][2]; t3 += a[q][3]; }
    float4 sn = *(const float4*)(s + (size_t)node * 4);
    float* base = accL[t >> 6][gi];
#pragma unroll
    for (int i = 0; i < 16; ++i) {
      int idx = (i + t) & 15;  // stagger: 4-way instead of 64-way contention
      int hi = idx >> 2, lo = idx & 3;
      float a1 = (hi == 0) ? sn.x : (hi == 1) ? sn.y : (hi == 2) ? sn.z : sn.w;
      float b1 = (lo == 0) ? t0 : (lo == 1) ? t1 : (lo == 2) ? t2 : t3;
      atomicAdd(base + idx, a1 * b1);
    }
  }
  __syncthreads();
  if (t < 32) {
    int gi = t >> 4, i = t & 15, gg = g0 + gi;
    if (gg < NB) {
      float v = accL[0][gi][i] + accL[1][gi][i] + accL[2][gi][i] + accL[3][gi][i];
      atomicAdd(&adjraw[gg * 16 + i], v);
    }
  }
}

// ---------------------------------------------------------------- K5: per-graph tail + losses (k_graph + k_final merged; 1 block)
__global__ __launch_bounds__(1024) void k_tail(
    const float* __restrict__ out_pool, const float* __restrict__ adjraw,
    const float* __restrict__ den_g, const float* __restrict__ ss_g,
    const float* __restrict__ Wrel3, const float* __restrict__ brel3,
    const float* __restrict__ Wroot3, const float* __restrict__ Wlin1,
    const float* __restrict__ blin1, const float* __restrict__ Wlin2,
    const float* __restrict__ blin2, float* __restrict__ d_out,
    float* __restrict__ scratch) {
  const int g = threadIdx.x >> 7;   // graph 0..7
  const int tt = threadIdx.x & 127;
  __shared__ float adjL[NB][16], adjnL[NB][16], dL[NB][4];
  __shared__ float osL[NB][128], msL[NB][128], x2mL[NB][128], x3L[NB][128];
  if (tt < 16) adjL[g][tt] = adjraw[g * 16 + tt];
  __syncthreads();
  if (tt < 4) {
    float srow = 0.f;
#pragma unroll
    for (int l = 0; l < 4; ++l)
      if (l != tt) srow += adjL[g][tt * 4 + l];
    dL[g][tt] = sqrtf(srow) + 1e-15f;
  }
  __syncthreads();
  if (tt < 16) {
    int k1 = tt >> 2, k2 = tt & 3;
    float az = (k1 == k2) ? 0.f : adjL[g][tt];
    float an = az / (dL[g][k2] * dL[g][k1]);
    adjnL[g][tt] = an;
    d_out[400018 + g * 16 + tt] = an;
  }
  __syncthreads();
  float o0 = out_pool[g * 512 + 0 * 128 + tt];
  float o1 = out_pool[g * 512 + 1 * 128 + tt];
  float o2 = out_pool[g * 512 + 2 * 128 + tt];
  float o3 = out_pool[g * 512 + 3 * 128 + tt];
  float m0 = adjnL[g][0] * o0 + adjnL[g][1] * o1 + adjnL[g][2] * o2 + adjnL[g][3] * o3;
  float m1 = adjnL[g][4] * o0 + adjnL[g][5] * o1 + adjnL[g][6] * o2 + adjnL[g][7] * o3;
  float m2 = adjnL[g][8] * o0 + adjnL[g][9] * o1 + adjnL[g][10] * o2 + adjnL[g][11] * o3;
  float m3 = adjnL[g][12] * o0 + adjnL[g][13] * o1 + adjnL[g][14] * o2 + adjnL[g][15] * o3;
  osL[g][tt] = o0 + o1 + o2 + o3;
  msL[g][tt] = m0 + m1 + m2 + m3;
  __syncthreads();
  float accc = brel3[tt];
  for (int j = 0; j < 128; ++j)
    accc += 0.25f * (msL[g][j] * Wrel3[j * 128 + tt] + osL[g][j] * Wroot3[j * 128 + tt]);
  x2mL[g][tt] = accc;
  __syncthreads();
  float a2 = blin1[tt];
  for (int j = 0; j < 128; ++j) a2 += x2mL[g][j] * Wlin1[j * 128 + tt];
  x3L[g][tt] = fmaxf(a2, 0.f);
  __syncthreads();
  if (tt < 2) {
    float lg = blin2[tt];
    for (int j = 0; j < 128; ++j) lg += x3L[g][j] * Wlin2[j * 2 + tt];
    scratch[g * 2 + tt] = lg;
  }
  if (tt == 0) {
    float tr = adjL[g][0] + adjL[g][5] + adjL[g][10] + adjL[g][15];
    scratch[16 + g] = tr / den_g[g];
    float n2 = 0.f;
    for (int i = 0; i < 16; ++i) { float v = ss_g[g * 16 + i]; n2 += v * v; }
    float nn = sqrtf(n2);
    float od = 0.f;
    for (int i = 0; i < 16; ++i) {
      float v = ss_g[g * 16 + i] / nn - (((i >> 2) == (i & 3)) ? 0.5f : 0.f);
      od += v * v;
    }
    scratch[24 + g] = sqrtf(od);
  }
  __syncthreads();
  if (threadIdx.x == 0) {
    float mc = 0.f, oo = 0.f;
    for (int b = 0; b < NB; ++b) { mc += scratch[16 + b]; oo += scratch[24 + b]; }
    d_out[16] = -(mc / (float)NB);
    d_out[17] = oo / (float)NB;
    for (int b = 0; b < NB; ++b) {
      float l0 = scratch[2 * b], l1 = scratch[2 * b + 1];
      float m = fmaxf(l0, l1);
      float lse = m + logf(expf(l0 - m) + expf(l1 - m));
      d_out[2 * b] = l0 - lse;
      d_out[2 * b + 1] = l1 - lse;
    }
  }
}

// ---------------------------------------------------------------- launch
extern "C" void kernel_launch(void* const* d_in, const int* in_sizes, int n_in,
                              void* d_out, int out_size, void* d_ws, size_t ws_size,
                              hipStream_t stream) {
  (void)in_sizes; (void)n_in; (void)out_size; (void)ws_size;
  const float* x      = (const float*)d_in[0];
  const int*   ei     = (const int*)d_in[1];
  const float* Wroot1 = (const float*)d_in[3];
  const float* Wrel1  = (const float*)d_in[4];
  const float* brel1  = (const float*)d_in[5];
  const float* Wpool  = (const float*)d_in[6];
  const float* bpool  = (const float*)d_in[7];
  const float* Wrel3  = (const float*)d_in[8];
  const float* brel3  = (const float*)d_in[9];
  const float* Wroot3 = (const float*)d_in[10];
  const float* Wlin1  = (const float*)d_in[11];
  const float* blin1  = (const float*)d_in[12];
  const float* Wlin2  = (const float*)d_in[13];
  const float* blin2  = (const float*)d_in[14];
  float* out = (float*)d_out;

  char* ws = (char*)d_ws;
  float*  out_pool = (float*)(ws + 0);          //  16384 B (zeroed by k_prep)
  float*  ss_g     = (float*)(ws + 16384);      //    512 B
  float*  adjraw   = (float*)(ws + 16896);      //    512 B
  float*  den_g    = (float*)(ws + 17408);      //     32 B
  float*  scratch  = (float*)(ws + 17440);      //    128 B
  int*    sbcnt    = (int*)(ws + 17568);        //   1568 B
  ushort* zrow     = (ushort*)(ws + 19136);     //    256 B zeros
  float*  zf       = (float*)(ws + 19392);      //     16 B zeros (region ends 19648)
  int*    count    = (int*)(ws + 21248);        // 400000 B
  int*    rowptr   = (int*)(ws + 421248);       // 400016 B
  ushort* Wt       = (ushort*)(ws + 821264);    //  65536 B [128][256]
  int*    csr      = (int*)(ws + 886800);       // 6400000 B [E]
  ushort* xb       = (ushort*)(ws + 7286800);   // 25600000 B [N][128] bf16
  ushort* aggb     = (ushort*)(ws + 32886800);  // 25600000 B [N][128] bf16
  uint*   gbuf     = (uint*)(ws + 58486800);    // 8028160 B
  ushort* hbuf     = (ushort*)(ws + 66514960);  // 25600000 B [N][128] bf16

  k_prep<<<12629, 256, 0, stream>>>((const float4*)x, xb, Wrel1, Wroot1, Wt,
                                    (uint*)ws);
  k_bucket2<<<196, 256, 0, stream>>>(ei, sbcnt, gbuf);
  k_csr_tile<<<NBIN, 256, 0, stream>>>(gbuf, sbcnt, rowptr, count, csr);
  k_agg2<<<8 * ((BLK + 7) / 8), 256, 0, stream>>>(xb, count, rowptr, csr, zrow, aggb);
  k_gemm<<<NB * CHUNKS, 256, 0, stream>>>(aggb, xb, Wt, brel1, hbuf);
  k_epi<<<NB * CHUNKS, 256, 0, stream>>>(hbuf, Wpool, bpool, count, out + 18,
                                         out_pool, ss_g, den_g);
  k_adj2<<<(NN + 255) / 256, 256, 0, stream>>>(count, rowptr, csr, out + 18, zf, adjraw);
  k_tail<<<1, 1024, 0, stream>>>(out_pool, adjraw, den_g, ss_g, Wrel3, brel3, Wroot3,
                                 Wlin1, blin1, Wlin2, blin2, out, scratch);
}

// Round 20
// 180.388 us; speedup vs baseline: 1.3415x; 1.1231x over previous
//
#include <hip/hip_runtime.h>

// Problem constants (fixed by the reference)
#define NN     100000      // nodes
#define EE     1600000     // edges
#define NB     8           // graphs
#define BLK    12500       // nodes per graph
#define HID    128
#define KC     4
#define CHUNKS 196         // ceil(12500/64)
#define NTILE  49          // dst-ranges of 256 nodes per graph
#define NBIN   392         // 8 graphs x 49 tiles
#define GCAPS  5120        // per-bin capacity (mean 4081, sigma ~64)

typedef __attribute__((ext_vector_type(8))) short bf16x8;
typedef __attribute__((ext_vector_type(4))) float f32x4;

__device__ __forceinline__ ushort f2bf(float f) {
  uint u = __float_as_uint(f);
  return (ushort)((u + 0x7FFFu + ((u >> 16) & 1u)) >> 16);  // RNE
}
__device__ __forceinline__ float bf2f(ushort h) {
  return __uint_as_float(((uint)h) << 16);
}

#define GLL16(g, l) \
  __builtin_amdgcn_global_load_lds((const __attribute__((address_space(1))) void*)(g), \
                                   (__attribute__((address_space(3))) void*)(l), 16, 0, 0)

// ---------------------------------------------------------------- K0: [edge bucketing (blocks 0..195)] || [x->bf16 + Wt transpose]
// Independent work merged for concurrency: bucket blocks FIRST so they run
// under the 12.6K-block conversion. sbcnt is pre-zeroed by hipMemsetAsync.
__global__ __launch_bounds__(256) void k_prep(const float4* __restrict__ x4,
                                              ushort* __restrict__ xb,
                                              const float* __restrict__ Wrel1,
                                              const float* __restrict__ Wroot1,
                                              ushort* __restrict__ Wt,
                                              const int* __restrict__ ei,
                                              int* __restrict__ sbcnt,
                                              uint* __restrict__ gbuf) {
  __shared__ uint stage[8192];
  __shared__ int cnt[NBIN], start[NBIN + 1], rbase[NBIN];
  __shared__ int gtot[8], gb[8];
  const int bi = blockIdx.x;
  const int t = threadIdx.x;
  if (bi >= 196) {
    const int pb = bi - 196;
    if (pb < 12500) {
      int i = pb * 256 + t;  // 3.2M float4s exactly
      float4 v = x4[i];
      ushort4 r;
      r.x = f2bf(v.x); r.y = f2bf(v.y); r.z = f2bf(v.z); r.w = f2bf(v.w);
      *(ushort4*)(xb + (size_t)i * 4) = r;
    } else {
      int col = pb - 12500, k = t;
      float v = (k < 128) ? Wrel1[k * 128 + col] : Wroot1[(k - 128) * 128 + col];
      Wt[col * 256 + k] = f2bf(v);
    }
    return;
  }
  // ---- bucket role (blocks 0..195) ----
  for (int b = t; b < NBIN; b += 256) cnt[b] = 0;
  __syncthreads();
  const int e0 = bi * 8192;
  uint pk[32]; int br[32];
#pragma unroll
  for (int i = 0; i < 32; ++i) {
    int e = e0 + i * 256 + t;
    bool val = (e < EE);
    int src = 0, dst = 0;
    if (val) {
      src = __builtin_nontemporal_load(ei + e);
      dst = __builtin_nontemporal_load(ei + EE + e);
    }
    int g = dst / BLK;
    int dl = dst - g * BLK;
    int sl = src - g * BLK;
    int bin = g * NTILE + (dl >> 8);
    pk[i] = ((uint)sl << 16) | (uint)dl;
    br[i] = val ? ((bin << 14) | atomicAdd(&cnt[bin], 1)) : -1;
  }
  __syncthreads();
  if (t < 8) {
    int s = 0;
    for (int k = 0; k < NTILE; ++k) s += cnt[t * NTILE + k];
    gtot[t] = s;
  }
  __syncthreads();
  if (t == 0) {
    int s = 0;
    for (int g = 0; g < 8; ++g) { gb[g] = s; s += gtot[g]; }
    start[NBIN] = s;
  }
  __syncthreads();
  if (t < 8) {
    int run = gb[t];
    for (int k = 0; k < NTILE; ++k) { start[t * NTILE + k] = run; run += cnt[t * NTILE + k]; }
  }
  __syncthreads();
  for (int b = t; b < NBIN; b += 256) rbase[b] = atomicAdd(&sbcnt[b], cnt[b]);
#pragma unroll
  for (int i = 0; i < 32; ++i) {
    if (br[i] >= 0) {
      int bin = br[i] >> 14, rank = br[i] & 16383;
      stage[start[bin] + rank] = pk[i];
    }
  }
  __syncthreads();
  for (int b = t; b < NBIN; b += 256) {
    const int n = cnt[b];
    const int s0 = start[b];
    uint* dst = gbuf + (size_t)b * GCAPS + rbase[b];
    for (int i = 0; i < n; ++i) dst[i] = stage[s0 + i];
  }
}

// ---------------------------------------------------------------- K1: per-bin LDS counting sort -> dense CSR (scan inlined)
__global__ __launch_bounds__(256) void k_csr_tile(const uint* __restrict__ gbuf,
                                                  const int* __restrict__ sbcnt,
                                                  int* __restrict__ rowptr,
                                                  int* __restrict__ count,
                                                  int* __restrict__ csr) {
  const int g = blockIdx.x & 7;     // XCD-local per graph
  const int tile = blockIdx.x >> 3; // 0..48
  const int bin = g * NTILE + tile;
  const int m = sbcnt[bin];
  const int n0t = tile * 256;
  const int nt = min(256, BLK - n0t);
  __shared__ uint ent[GCAPS];
  __shared__ ushort srt[GCAPS];
  __shared__ int cnt[256], scn[256], cur[256];
  __shared__ int red[256];
  const int t = threadIdx.x;
  {
    int partial = 0;
    for (int i = t; i < bin; i += 256) partial += sbcnt[i];
    red[t] = partial;
    __syncthreads();
    for (int off = 128; off > 0; off >>= 1) {
      if (t < off) red[t] += red[t + off];
      __syncthreads();
    }
  }
  const int base = red[0];
  cnt[t] = 0;
  __syncthreads();
  const uint* buf = gbuf + (size_t)bin * GCAPS;
  for (int i = t; i < m; i += 256) {
    uint pk = buf[i];
    ent[i] = pk;
    atomicAdd(&cnt[(int)(pk & 0xFFFFu) - n0t], 1);
  }
  __syncthreads();
  int v = cnt[t];
  scn[t] = v;
  __syncthreads();
  for (int s = 1; s < 256; s <<= 1) {
    int x = (t >= s) ? scn[t - s] : 0;
    __syncthreads();
    scn[t] += x;
    __syncthreads();
  }
  int excl = scn[t] - v;
  cur[t] = excl;
  if (t < nt) {
    rowptr[g * BLK + n0t + t] = base + excl;
    count[g * BLK + n0t + t] = v;
  }
  __syncthreads();
  for (int i = t; i < m; i += 256) {
    uint pk = ent[i];
    int p = atomicAdd(&cur[(int)(pk & 0xFFFFu) - n0t], 1);
    srt[p] = (ushort)(pk >> 16);
  }
  __syncthreads();
  const int nb = g * BLK;
  for (int i = t; i < m; i += 256)
    csr[base + i] = nb + (int)srt[i];  // dense coalesced
}

// ---------------------------------------------------------------- K2: agg[n] = sum_{e: dst=n} x[src]  (R18 structure, best measured)
__global__ __launch_bounds__(256) void k_agg2(const ushort* __restrict__ xb,
                                              const int* __restrict__ count,
                                              const int* __restrict__ rowptr,
                                              const int* __restrict__ csr,
                                              const ushort* __restrict__ zrow,
                                              ushort* __restrict__ aggb) {
  const int xg = blockIdx.x & 7;
  const int j = blockIdx.x >> 3;
  const int half = threadIdx.x >> 5;  // 8 half-waves = 8 nodes per block
  const int lane = threadIdx.x & 31;
  const int ln = j * 8 + half;
  if (ln >= BLK) return;
  const int node = xg * BLK + ln;
  const int deg = count[node];
  const int* sl = csr + rowptr[node];
  int idx0 = (lane < deg) ? sl[lane] : 0;
  int idx1 = (32 + lane < deg) ? sl[32 + lane] : 0;
  const ushort* zr = zrow + lane * 4;

  float4 acc[8];
#pragma unroll
  for (int q = 0; q < 8; ++q) acc[q] = (float4){0.f, 0.f, 0.f, 0.f};

  const int nb8 = (deg + 7) >> 3;
  for (int b = 0; b < nb8; ++b) {
    const int e = b * 8;
    const ushort* ps[8];
#pragma unroll
    for (int q = 0; q < 8; ++q) {
      int ee = e + q;
      int si = (ee < 32) ? __shfl(idx0, ee, 32)
             : ((ee < 64) ? __shfl(idx1, ee - 32, 32)
                          : ((ee < deg) ? sl[ee] : 0));
      ps[q] = (ee < deg) ? (xb + (size_t)si * HID + lane * 4) : zr;
    }
    uint2 v[8];
#pragma unroll
    for (int q = 0; q < 8; ++q) v[q] = *(const uint2*)ps[q];
#pragma unroll
    for (int q = 0; q < 8; ++q) {
      acc[q].x += __uint_as_float(v[q].x << 16);
      acc[q].y += __uint_as_float(v[q].x & 0xFFFF0000u);
      acc[q].z += __uint_as_float(v[q].y << 16);
      acc[q].w += __uint_as_float(v[q].y & 0xFFFF0000u);
    }
  }

  float lo0 = 0.f, hi0 = 0.f, lo1 = 0.f, hi1 = 0.f;
#pragma unroll
  for (int q = 0; q < 8; ++q) { lo0 += acc[q].x; hi0 += acc[q].y; lo1 += acc[q].z; hi1 += acc[q].w; }
  ushort4 r;
  r.x = f2bf(lo0); r.y = f2bf(hi0); r.z = f2bf(lo1); r.w = f2bf(hi1);
  *(ushort4*)(aggb + (size_t)node * HID + lane * 4) = r;
}

// ---------------------------------------------------------------- K3: GEMM + bias/relu -> hbuf + pooling head -> s (s moved here from epi)
__global__ __launch_bounds__(256) void k_gemm(
    const ushort* __restrict__ aggb, const ushort* __restrict__ xb,
    const ushort* __restrict__ Wt, const float* __restrict__ brel1,
    const float* __restrict__ Wpool, const float* __restrict__ bpool,
    ushort* __restrict__ hbuf, float* __restrict__ s_out) {
  __shared__ ushort Aag_s[64][128];  // 16 KB, linear (DMA dest)
  __shared__ ushort Ax_s[64][128];   // 16 KB, linear (DMA dest)
  __shared__ ushort hLb[64][136];    // h tile bf16 (pad 136)

  const int t = threadIdx.x;
  const int bi = blockIdx.x;
  const int bG = bi & 7;
  const int chunk = bi >> 3;
  const int node0 = bG * BLK + chunk * 64;
  int nrows = BLK - chunk * 64;
  if (nrows > 64) nrows = 64;

  const int w = t >> 6;
  const int l = t & 63;

  // async stage: 8 global_load_lds per wave (4 agg + 4 x tiles)
  {
    const int sub = l >> 4;
    const int c16 = l & 15;
#pragma unroll
    for (int i = 0; i < 4; ++i) {
      const int j = w * 4 + i;
      const int row = j * 4 + sub;
      const int rs = (row < nrows) ? row : (nrows - 1);
      const int boff = (c16 * 16) ^ ((row & 7) << 4);
      const ushort* ga = aggb + (size_t)(node0 + rs) * HID + (boff >> 1);
      const ushort* gx = xb + (size_t)(node0 + rs) * HID + (boff >> 1);
      GLL16(ga, &Aag_s[j * 4][0]);
      GLL16(gx, &Ax_s[j * 4][0]);
    }
  }

  const int m16 = l & 15;
  const int gq = l >> 4;

  bf16x8 Breg[8][2];
#pragma unroll
  for (int kt = 0; kt < 8; ++kt)
#pragma unroll
    for (int fc = 0; fc < 2; ++fc)
      Breg[kt][fc] =
          *(const bf16x8*)(Wt + (size_t)(32 * w + 16 * fc + m16) * 256 + kt * 32 + 8 * gq);

  f32x4 acc[4][2];
#pragma unroll
  for (int fr = 0; fr < 4; ++fr)
#pragma unroll
    for (int fc = 0; fc < 2; ++fc) acc[fr][fc] = (f32x4){0.f, 0.f, 0.f, 0.f};

  asm volatile("s_waitcnt vmcnt(0)" ::: "memory");
  __syncthreads();

#pragma unroll
  for (int kt = 0; kt < 8; ++kt) {
    const int k4 = kt & 3;
    bf16x8 af[4];
#pragma unroll
    for (int fr = 0; fr < 4; ++fr) {
      const int r = 16 * fr + m16;
      const int ci = (k4 * 32 + gq * 8) ^ ((r & 7) << 3);
      af[fr] = (kt < 4) ? *(const bf16x8*)&Aag_s[r][ci]
                        : *(const bf16x8*)&Ax_s[r][ci];
    }
#pragma unroll
    for (int fr = 0; fr < 4; ++fr)
#pragma unroll
      for (int fc = 0; fc < 2; ++fc)
        acc[fr][fc] = __builtin_amdgcn_mfma_f32_16x16x32_bf16(af[fr], Breg[kt][fc],
                                                              acc[fr][fc], 0, 0, 0);
  }

  const float bc0 = brel1[32 * w + m16];
  const float bc1 = brel1[32 * w + 16 + m16];
#pragma unroll
  for (int fr = 0; fr < 4; ++fr)
#pragma unroll
    for (int fc = 0; fc < 2; ++fc)
#pragma unroll
      for (int r = 0; r < 4; ++r)
        hLb[16 * fr + 4 * gq + r][32 * w + 16 * fc + m16] =
            f2bf(fmaxf(acc[fr][fc][r] + (fc ? bc1 : bc0), 0.f));
  __syncthreads();

  // dense h store: thread t -> row t>>2, 64 B chunk (t&3)
  {
    const int row = t >> 2;
    const int ch = (t & 3) * 32;
    if (row < nrows) {
      ushort* dst = hbuf + (size_t)(node0 + row) * HID + ch;
      const ushort* src = &hLb[row][ch];
#pragma unroll
      for (int q = 0; q < 4; ++q)
        *(bf16x8*)(dst + q * 8) = *(const bf16x8*)(src + q * 8);
    }
  }

  // ---- pooling head + softmax -> s (from k_epi, verbatim layout) ----
  const int g4 = t >> 4;
  const int c0 = (t & 15) << 2;
  const int li = t & 15;

  float h[4][8];
#pragma unroll
  for (int r = 0; r < 4; ++r) {
    ushort4 v0 = *(const ushort4*)&hLb[g4 * 4 + r][c0];
    ushort4 v1 = *(const ushort4*)&hLb[g4 * 4 + r][c0 + 64];
    h[r][0] = bf2f(v0.x); h[r][1] = bf2f(v0.y); h[r][2] = bf2f(v0.z); h[r][3] = bf2f(v0.w);
    h[r][4] = bf2f(v1.x); h[r][5] = bf2f(v1.y); h[r][6] = bf2f(v1.z); h[r][7] = bf2f(v1.w);
  }
  float wp[8][4];
#pragma unroll
  for (int j = 0; j < 8; ++j) {
    int col = c0 + (j & 3) + (j >> 2) * 64;
    float4 v = *(const float4*)(Wpool + col * 4);
    wp[j][0] = v.x; wp[j][1] = v.y; wp[j][2] = v.z; wp[j][3] = v.w;
  }
  float pp[4][4];
#pragma unroll
  for (int r = 0; r < 4; ++r)
#pragma unroll
    for (int k = 0; k < 4; ++k) pp[r][k] = 0.f;
#pragma unroll
  for (int r = 0; r < 4; ++r)
#pragma unroll
    for (int j = 0; j < 8; ++j)
#pragma unroll
      for (int k = 0; k < 4; ++k) pp[r][k] = fmaf(h[r][j], wp[j][k], pp[r][k]);
#pragma unroll
  for (int m = 1; m <= 8; m <<= 1)
#pragma unroll
    for (int r = 0; r < 4; ++r)
#pragma unroll
      for (int k = 0; k < 4; ++k) pp[r][k] += __shfl_xor(pp[r][k], m);

  float4 bp4 = *(const float4*)bpool;
  float bp[4] = {bp4.x, bp4.y, bp4.z, bp4.w};
#pragma unroll
  for (int r = 0; r < 4; ++r) {
    float p[4];
#pragma unroll
    for (int k = 0; k < 4; ++k) p[k] = pp[r][k] + bp[k];
    float mx = fmaxf(fmaxf(p[0], p[1]), fmaxf(p[2], p[3]));
    float e0 = expf(p[0] - mx), e1 = expf(p[1] - mx), e2 = expf(p[2] - mx), e3 = expf(p[3] - mx);
    float inv = 1.f / (e0 + e1 + e2 + e3);
    // lane li writes (row li>>2, k li&3) of its group via lane-matched select
    int rW = li >> 2, kW = li & 3;
    if (r == rW && g4 * 4 + rW < nrows) {
      float val = (kW == 0) ? e0 * inv : (kW == 1) ? e1 * inv : (kW == 2) ? e2 * inv : e3 * inv;
      s_out[(node0 + g4 * 4 + rW) * 4 + kW] = val;
    }
  }
}

// ---------------------------------------------------------------- K4: [epi (blocks 0..1567)] || [adj (blocks 1568..1958)]
__global__ __launch_bounds__(256) void k_epiadj(
    const ushort* __restrict__ hbuf, const float* __restrict__ s_in,
    const int* __restrict__ count, const int* __restrict__ rowptr,
    const int* __restrict__ csr, const float* __restrict__ zf,
    float* __restrict__ out_pool, float* __restrict__ ss_g,
    float* __restrict__ den_g, float* __restrict__ adjraw) {
  __shared__ ushort hLb[64][136];
  __shared__ float outL[KC][HID];
  __shared__ float ssL[16];
  __shared__ float denL;
  __shared__ float accL[4][2][16];
  const int t = threadIdx.x;
  const int bi = blockIdx.x;

  if (bi >= NB * CHUNKS) {
    // ---- adj role ----
    const int abi = bi - NB * CHUNKS;
    if (t < 128) ((float*)accL)[t] = 0.f;
    __syncthreads();
    const int node = abi * 256 + t;
    const int g0 = (abi * 256) / BLK;
    if (node < NN) {
      const int gi = node / BLK - g0;
      const int deg = count[node];
      const int* sl = csr + rowptr[node];
      float a[8][4];
#pragma unroll
      for (int q = 0; q < 8; ++q)
#pragma unroll
        for (int c = 0; c < 4; ++c) a[q][c] = 0.f;
      const int nb8 = (deg + 7) >> 3;
      for (int b = 0; b < nb8; ++b) {
        const float* p[8];
#pragma unroll
        for (int q = 0; q < 8; ++q) {
          int ee = b * 8 + q;
          int si = (ee < deg) ? sl[ee] : 0;
          p[q] = (ee < deg) ? (s_in + (size_t)si * 4) : zf;
        }
        float4 v[8];
#pragma unroll
        for (int q = 0; q < 8; ++q) v[q] = *(const float4*)p[q];
#pragma unroll
        for (int q = 0; q < 8; ++q) {
          a[q][0] += v[q].x; a[q][1] += v[q].y; a[q][2] += v[q].z; a[q][3] += v[q].w;
        }
      }
      float t0 = 0.f, t1 = 0.f, t2 = 0.f, t3 = 0.f;
#pragma unroll
      for (int q = 0; q < 8; ++q) { t0 += a[q][0]; t1 += a[q][1]; t2 += a[q][2]; t3 += a[q][3]; }
      float4 sn = *(const float4*)(s_in + (size_t)node * 4);
      float* base = accL[t >> 6][gi];
#pragma unroll
      for (int i = 0; i < 16; ++i) {
        int idx = (i + t) & 15;
        int hi = idx >> 2, lo = idx & 3;
        float a1 = (hi == 0) ? sn.x : (hi == 1) ? sn.y : (hi == 2) ? sn.z : sn.w;
        float b1 = (lo == 0) ? t0 : (lo == 1) ? t1 : (lo == 2) ? t2 : t3;
        atomicAdd(base + idx, a1 * b1);
      }
    }
    __syncthreads();
    if (t < 32) {
      int gi = t >> 4, i = t & 15, gg = g0 + gi;
      if (gg < NB) {
        float v = accL[0][gi][i] + accL[1][gi][i] + accL[2][gi][i] + accL[3][gi][i];
        atomicAdd(&adjraw[gg * 16 + i], v);
      }
    }
    return;
  }

  // ---- epi role ----
  const int bG = bi & 7;
  const int chunk = bi >> 3;
  const int node0 = bG * BLK + chunk * 64;
  int nrows = BLK - chunk * 64;
  if (nrows > 64) nrows = 64;

  {
    const int row = t >> 2;
    const int ch = (t & 3) * 32;
    const int rs = (row < nrows) ? row : (nrows - 1);
    const ushort* src = hbuf + (size_t)(node0 + rs) * HID + ch;
    ushort* dst = &hLb[row][ch];
#pragma unroll
    for (int q = 0; q < 4; ++q)
      *(bf16x8*)(dst + q * 8) = *(const bf16x8*)(src + q * 8);
  }

  for (int i = t; i < KC * HID; i += 256) ((float*)outL)[i] = 0.f;
  if (t < 16) ssL[t] = 0.f;
  if (t == 0) denL = 0.f;
  __syncthreads();

  const int g4 = t >> 4;
  const int c0 = (t & 15) << 2;
  const int li = t & 15;

  float h[4][8];
#pragma unroll
  for (int r = 0; r < 4; ++r) {
    ushort4 v0 = *(const ushort4*)&hLb[g4 * 4 + r][c0];
    ushort4 v1 = *(const ushort4*)&hLb[g4 * 4 + r][c0 + 64];
    h[r][0] = bf2f(v0.x); h[r][1] = bf2f(v0.y); h[r][2] = bf2f(v0.z); h[r][3] = bf2f(v0.w);
    h[r][4] = bf2f(v1.x); h[r][5] = bf2f(v1.y); h[r][6] = bf2f(v1.z); h[r][7] = bf2f(v1.w);
  }

  // load s (computed in k_gemm)
  float sv[4][4];
#pragma unroll
  for (int r = 0; r < 4; ++r) {
    int rowg = g4 * 4 + r;
    float4 sval = (float4){0.f, 0.f, 0.f, 0.f};
    if (rowg < nrows) sval = *(const float4*)(s_in + (size_t)(node0 + rowg) * 4);
    sv[r][0] = sval.x; sv[r][1] = sval.y; sv[r][2] = sval.z; sv[r][3] = sval.w;
  }

  // ss[b][k1][k2]
  {
    int k1 = li >> 2, k2 = li & 3;
    float a1[4], a2[4];
#pragma unroll
    for (int rr = 0; rr < 4; ++rr) {
      float v1 = 0.f, v2 = 0.f;
#pragma unroll
      for (int kk = 0; kk < 4; ++kk) {
        if (k1 == kk) v1 = sv[rr][kk];
        if (k2 == kk) v2 = sv[rr][kk];
      }
      a1[rr] = v1; a2[rr] = v2;
    }
    float ssv = a1[0] * a2[0] + a1[1] * a2[1] + a1[2] * a2[2] + a1[3] * a2[3];
    atomicAdd(&ssL[li], ssv);
  }

  // den += deg * ||s||^2
  if (li == 0) {
    float dent = 0.f;
#pragma unroll
    for (int rr = 0; rr < 4; ++rr) {
      int rowg = g4 * 4 + rr;
      if (rowg < nrows) {
        float dg = (float)count[node0 + rowg];
        dent += dg * (sv[rr][0] * sv[rr][0] + sv[rr][1] * sv[rr][1] +
                      sv[rr][2] * sv[rr][2] + sv[rr][3] * sv[rr][3]);
      }
    }
    atomicAdd(&denL, dent);
  }

  // out[k][c] += s[r][k]*h[r][c]
  float po[4][8];
#pragma unroll
  for (int k = 0; k < 4; ++k)
#pragma unroll
    for (int c = 0; c < 8; ++c) po[k][c] = 0.f;
#pragma unroll
  for (int k = 0; k < 4; ++k)
#pragma unroll
    for (int rr = 0; rr < 4; ++rr)
#pragma unroll
      for (int c = 0; c < 8; ++c) po[k][c] = fmaf(sv[rr][k], h[rr][c], po[k][c]);
#pragma unroll
  for (int k = 0; k < 4; ++k)
#pragma unroll
    for (int c = 0; c < 8; ++c) {
      po[k][c] += __shfl_xor(po[k][c], 16);
      po[k][c] += __shfl_xor(po[k][c], 32);
    }
  if ((t & 63) < 16) {
#pragma unroll
    for (int k = 0; k < 4; ++k)
#pragma unroll
      for (int c = 0; c < 8; ++c)
        atomicAdd(&outL[k][c0 + (c & 3) + (c >> 2) * 64], po[k][c]);
  }

  __syncthreads();
  for (int i = t; i < KC * HID; i += 256)
    atomicAdd(&out_pool[bG * KC * HID + i], ((const float*)outL)[i]);
  if (t < 16) atomicAdd(&ss_g[bG * 16 + t], ssL[t]);
  if (t == 0) atomicAdd(&den_g[bG], denL);
}

// ---------------------------------------------------------------- K5: per-graph tail + losses (1 block)
__global__ __launch_bounds__(1024) void k_tail(
    const float* __restrict__ out_pool, const float* __restrict__ adjraw,
    const float* __restrict__ den_g, const float* __restrict__ ss_g,
    const float* __restrict__ Wrel3, const float* __restrict__ brel3,
    const float* __restrict__ Wroot3, const float* __restrict__ Wlin1,
    const float* __restrict__ blin1, const float* __restrict__ Wlin2,
    const float* __restrict__ blin2, float* __restrict__ d_out,
    float* __restrict__ scratch) {
  const int g = threadIdx.x >> 7;   // graph 0..7
  const int tt = threadIdx.x & 127;
  __shared__ float adjL[NB][16], adjnL[NB][16], dL[NB][4];
  __shared__ float osL[NB][128], msL[NB][128], x2mL[NB][128], x3L[NB][128];
  if (tt < 16) adjL[g][tt] = adjraw[g * 16 + tt];
  __syncthreads();
  if (tt < 4) {
    float srow = 0.f;
#pragma unroll
    for (int l = 0; l < 4; ++l)
      if (l != tt) srow += adjL[g][tt * 4 + l];
    dL[g][tt] = sqrtf(srow) + 1e-15f;
  }
  __syncthreads();
  if (tt < 16) {
    int k1 = tt >> 2, k2 = tt & 3;
    float az = (k1 == k2) ? 0.f : adjL[g][tt];
    float an = az / (dL[g][k2] * dL[g][k1]);
    adjnL[g][tt] = an;
    d_out[400018 + g * 16 + tt] = an;
  }
  __syncthreads();
  float o0 = out_pool[g * 512 + 0 * 128 + tt];
  float o1 = out_pool[g * 512 + 1 * 128 + tt];
  float o2 = out_pool[g * 512 + 2 * 128 + tt];
  float o3 = out_pool[g * 512 + 3 * 128 + tt];
  float m0 = adjnL[g][0] * o0 + adjnL[g][1] * o1 + adjnL[g][2] * o2 + adjnL[g][3] * o3;
  float m1 = adjnL[g][4] * o0 + adjnL[g][5] * o1 + adjnL[g][6] * o2 + adjnL[g][7] * o3;
  float m2 = adjnL[g][8] * o0 + adjnL[g][9] * o1 + adjnL[g][10] * o2 + adjnL[g][11] * o3;
  float m3 = adjnL[g][12] * o0 + adjnL[g][13] * o1 + adjnL[g][14] * o2 + adjnL[g][15] * o3;
  osL[g][tt] = o0 + o1 + o2 + o3;
  msL[g][tt] = m0 + m1 + m2 + m3;
  __syncthreads();
  float accc = brel3[tt];
  for (int j = 0; j < 128; ++j)
    accc += 0.25f * (msL[g][j] * Wrel3[j * 128 + tt] + osL[g][j] * Wroot3[j * 128 + tt]);
  x2mL[g][tt] = accc;
  __syncthreads();
  float a2 = blin1[tt];
  for (int j = 0; j < 128; ++j) a2 += x2mL[g][j] * Wlin1[j * 128 + tt];
  x3L[g][tt] = fmaxf(a2, 0.f);
  __syncthreads();
  if (tt < 2) {
    float lg = blin2[tt];
    for (int j = 0; j < 128; ++j) lg += x3L[g][j] * Wlin2[j * 2 + tt];
    scratch[g * 2 + tt] = lg;
  }
  if (tt == 0) {
    float tr = adjL[g][0] + adjL[g][5] + adjL[g][10] + adjL[g][15];
    scratch[16 + g] = tr / den_g[g];
    float n2 = 0.f;
    for (int i = 0; i < 16; ++i) { float v = ss_g[g * 16 + i]; n2 += v * v; }
    float nn = sqrtf(n2);
    float od = 0.f;
    for (int i = 0; i < 16; ++i) {
      float v = ss_g[g * 16 + i] / nn - (((i >> 2) == (i & 3)) ? 0.5f : 0.f);
      od += v * v;
    }
    scratch[24 + g] = sqrtf(od);
  }
  __syncthreads();
  if (threadIdx.x == 0) {
    float mc = 0.f, oo = 0.f;
    for (int b = 0; b < NB; ++b) { mc += scratch[16 + b]; oo += scratch[24 + b]; }
    d_out[16] = -(mc / (float)NB);
    d_out[17] = oo / (float)NB;
    for (int b = 0; b < NB; ++b) {
      float l0 = scratch[2 * b], l1 = scratch[2 * b + 1];
      float m = fmaxf(l0, l1);
      float lse = m + logf(expf(l0 - m) + expf(l1 - m));
      d_out[2 * b] = l0 - lse;
      d_out[2 * b + 1] = l1 - lse;
    }
  }
}

// ---------------------------------------------------------------- launch
extern "C" void kernel_launch(void* const* d_in, const int* in_sizes, int n_in,
                              void* d_out, int out_size, void* d_ws, size_t ws_size,
                              hipStream_t stream) {
  (void)in_sizes; (void)n_in; (void)out_size; (void)ws_size;
  const float* x      = (const float*)d_in[0];
  const int*   ei     = (const int*)d_in[1];
  const float* Wroot1 = (const float*)d_in[3];
  const float* Wrel1  = (const float*)d_in[4];
  const float* brel1  = (const float*)d_in[5];
  const float* Wpool  = (const float*)d_in[6];
  const float* bpool  = (const float*)d_in[7];
  const float* Wrel3  = (const float*)d_in[8];
  const float* brel3  = (const float*)d_in[9];
  const float* Wroot3 = (const float*)d_in[10];
  const float* Wlin1  = (const float*)d_in[11];
  const float* blin1  = (const float*)d_in[12];
  const float* Wlin2  = (const float*)d_in[13];
  const float* blin2  = (const float*)d_in[14];
  float* out = (float*)d_out;

  char* ws = (char*)d_ws;
  float*  out_pool = (float*)(ws + 0);          //  16384 B (memset)
  float*  ss_g     = (float*)(ws + 16384);      //    512 B (memset)
  float*  adjraw   = (float*)(ws + 16896);      //    512 B (memset)
  float*  den_g    = (float*)(ws + 17408);      //     32 B (memset)
  float*  scratch  = (float*)(ws + 17440);      //    128 B (memset)
  int*    sbcnt    = (int*)(ws + 17568);        //   1568 B (memset)
  ushort* zrow     = (ushort*)(ws + 19136);     //    256 B zeros (memset)
  float*  zf       = (float*)(ws + 19392);      //     16 B zeros (region ends 19648)
  int*    count    = (int*)(ws + 21248);        // 400000 B
  int*    rowptr   = (int*)(ws + 421248);       // 400016 B
  ushort* Wt       = (ushort*)(ws + 821264);    //  65536 B [128][256]
  int*    csr      = (int*)(ws + 886800);       // 6400000 B [E]
  ushort* xb       = (ushort*)(ws + 7286800);   // 25600000 B [N][128] bf16
  ushort* aggb     = (ushort*)(ws + 32886800);  // 25600000 B [N][128] bf16
  uint*   gbuf     = (uint*)(ws + 58486800);    // 8028160 B
  ushort* hbuf     = (ushort*)(ws + 66514960);  // 25600000 B [N][128] bf16

  hipMemsetAsync(ws, 0, 19648, stream);
  k_prep<<<196 + 12500 + 128, 256, 0, stream>>>((const float4*)x, xb, Wrel1, Wroot1,
                                                Wt, ei, sbcnt, gbuf);
  k_csr_tile<<<NBIN, 256, 0, stream>>>(gbuf, sbcnt, rowptr, count, csr);
  k_agg2<<<8 * ((BLK + 7) / 8), 256, 0, stream>>>(xb, count, rowptr, csr, zrow, aggb);
  k_gemm<<<NB * CHUNKS, 256, 0, stream>>>(aggb, xb, Wt, brel1, Wpool, bpool, hbuf,
                                          out + 18);
  k_epiadj<<<NB * CHUNKS + (NN + 255) / 256, 256, 0, stream>>>(
      hbuf, out + 18, count, rowptr, csr, zf, out_pool, ss_g, den_g, adjraw);
  k_tail<<<1, 1024, 0, stream>>>(out_pool, adjraw, den_g, ss_g, Wrel3, brel3, Wroot3,
                                 Wlin1, blin1, Wlin2, blin2, out, scratch);
}